// Round 1
// 206.882 us; speedup vs baseline: 1.0313x; 1.0313x over previous
//
#include <hip/hip_runtime.h>
#include <hip/hip_bf16.h>

typedef unsigned short u16;
typedef __bf16 bf16x8 __attribute__((ext_vector_type(8)));
typedef float f32x4 __attribute__((ext_vector_type(4)));
typedef unsigned short u16x4 __attribute__((ext_vector_type(4)));

#define MFMA16(a, b, c) __builtin_amdgcn_mfma_f32_16x16x32_bf16(a, b, c, 0, 0, 0)

#define EMB 1024
#define SEQ 2048
#define NH 16
#define HD 64
#define LOG2E 1.4426950408889634f

// async global->LDS, 16B per lane; LDS dest = wave-uniform base + lane*16
#define GLOAD_LDS16(g, l) __builtin_amdgcn_global_load_lds( \
    (const __attribute__((address_space(1))) unsigned int*)(g), \
    (__attribute__((address_space(3))) unsigned int*)(l), 16, 0, 0)

__device__ __forceinline__ float b2f(u16 u) {
    union { unsigned int i; float f; } v; v.i = ((unsigned int)u) << 16; return v.f;
}
__device__ __forceinline__ u16 f2b(float f) {
    __hip_bfloat16 h = __float2bfloat16(f);
    return *reinterpret_cast<u16*>(&h);
}
__device__ __forceinline__ u16x4 pack4(float a, float b, float c, float d) {
    union { __hip_bfloat162 h2[2]; u16x4 u; } r;
    r.h2[0] = __float22bfloat162_rn(float2{a, b});
    r.h2[1] = __float22bfloat162_rn(float2{c, d});
    return r.u;
}
__device__ __forceinline__ bf16x8 ldfrag(const u16* p) {
    return *reinterpret_cast<const bf16x8*>(p);
}
__device__ __forceinline__ bf16x8 cvt8(const float* p) {
    const float4 a = *reinterpret_cast<const float4*>(p);
    const float4 b = *reinterpret_cast<const float4*>(p + 4);
    union { u16x4 q[2]; bf16x8 v; } r;
    r.q[0] = pack4(a.x, a.y, a.z, a.w);
    r.q[1] = pack4(b.x, b.y, b.z, b.w);
    return r.v;
}
// tanh via hw exp2 + rcp: rel err < 1e-6, safe for |x| < 40
// raw v_exp_f32 (no denormal-guard sequence); inf/0 endpoints saturate correctly
__device__ __forceinline__ float fast_tanh(float x) {
    float t = __builtin_amdgcn_exp2f(x * (2.0f * LOG2E));
    return 1.0f - 2.0f * __builtin_amdgcn_rcpf(t + 1.0f);
}
__device__ __forceinline__ bf16x8 tanh8(bf16x8 v) {
    union { bf16x8 v; u16 u[8]; } in; in.v = v;
    float o[8];
#pragma unroll
    for (int e = 0; e < 8; e++) o[e] = fast_tanh(b2f(in.u[e]));
    union { u16x4 q[2]; bf16x8 v; } r;
    r.q[0] = pack4(o[0], o[1], o[2], o[3]);
    r.q[1] = pack4(o[4], o[5], o[6], o[7]);
    return r.v;
}

// ---------------------------------------------------------------------------
// fp32 -> bf16 conversion: [x (4096x1024) | Wq | Wk | Wv | Wo] -> ws bf16
// ---------------------------------------------------------------------------
__global__ __launch_bounds__(256) void cvt_all(
        const float* __restrict__ x,  const float* __restrict__ Wq,
        const float* __restrict__ Wk, const float* __restrict__ Wv,
        const float* __restrict__ Wo, u16* __restrict__ dst)
{
    size_t i = ((size_t)blockIdx.x * 256 + threadIdx.x) * 8;
    const float* src; size_t off;
    if (i < 4194304) { src = x; off = i; }
    else {
        size_t j = i - 4194304; int w = (int)(j >> 20); off = j & 1048575;
        src = (w == 0) ? Wq : (w == 1) ? Wk : (w == 2) ? Wv : Wo;
    }
    *(bf16x8*)&dst[i] = cvt8(src + off);
}

// ---------------------------------------------------------------------------
// GEMM: C = A(MxK,bf16) @ W(NxK,bf16)^T + bias(fp32). Tile MI*32 x 128, BK=64.
// 256 thr = 4 waves (2x2). global_load_lds staging, XOR chunk swizzle (8 chunks
// per 64-elem row: col8 = cc ^ (row&7) -> 2-way banks on frag reads = free).
// mode 0: Qa[:,0:64]=Q/8*log2e, Qa[:,64:128]=lam*log2e*tanh(Q) (B,H,S,128)
// mode 1: Ka[:,0:64]=K                                (B,H,S,128) bf16
// mode 2: Vt[b,h,d,s]=V  (transposed)                 (B,H,HD,S)  bf16
// mode 3: out = val fp32 (row-major M x EMB)
// ---------------------------------------------------------------------------
template<int MI>   // m-frags per wave (4 -> 128-row tile, 2 -> 64-row tile)
__global__ __launch_bounds__(256, 4) void gemm_epi(
        const u16* __restrict__ A,
        const u16* __restrict__ W0, const float* __restrict__ B0,
        const u16* __restrict__ W1, const float* __restrict__ B1,
        const u16* __restrict__ W2, const float* __restrict__ B2,
        const float* __restrict__ lam,
        u16* __restrict__ Qa, u16* __restrict__ Ka, u16* __restrict__ Vt,
        float* __restrict__ out, int modeBase)
{
    const int mode = modeBase + blockIdx.z;
    const u16* W; const float* bias;
    if (blockIdx.z == 0)      { W = W0; bias = B0; }
    else if (blockIdx.z == 1) { W = W1; bias = B1; }
    else                      { W = W2; bias = B2; }

    __shared__ __attribute__((aligned(16))) u16 sA[MI * 32 * 64];
    __shared__ __attribute__((aligned(16))) u16 sB[128 * 64];

    const int t = threadIdx.x;
    const int w = t >> 6, L = t & 63;
    const int wm = w >> 1, wn = w & 1;
    const int lr = L & 15, lq = L >> 4;
    const int wbase = t & 192;                   // wave*64
    const int m0 = blockIdx.y * (MI * 32), n0 = blockIdx.x * 128;

    f32x4 acc[MI][4];
#pragma unroll
    for (int i = 0; i < MI; i++)
#pragma unroll
        for (int j = 0; j < 4; j++) { f32x4 z = {0.f, 0.f, 0.f, 0.f}; acc[i][j] = z; }

    for (int k0 = 0; k0 < EMB; k0 += 64) {
        __syncthreads();
        // stage A: MI*256 chunks of 8 elems (8 chunks/row), col8 = cc ^ (row&7)
#pragma unroll
        for (int q = 0; q < MI; q++) {
            int c = q * 256 + t;
            int row = c >> 3, cc = c & 7;
            int col8 = cc ^ (row & 7);
            GLOAD_LDS16(&A[(size_t)(m0 + row) * EMB + k0 + col8 * 8],
                        &sA[(q * 256 + wbase) * 8]);
        }
        // stage B: 1024 chunks
#pragma unroll
        for (int q = 0; q < 4; q++) {
            int c = q * 256 + t;
            int row = c >> 3, cc = c & 7;
            int col8 = cc ^ (row & 7);
            GLOAD_LDS16(&W[(size_t)(n0 + row) * EMB + k0 + col8 * 8],
                        &sB[(q * 256 + wbase) * 8]);
        }
        __syncthreads();
        // two 32-k sub-chunks; fragments loaded per sub-chunk to bound VGPR
#pragma unroll
        for (int s = 0; s < 2; s++) {
            bf16x8 af[MI], bfr[4];
#pragma unroll
            for (int mi = 0; mi < MI; mi++) {
                int row = wm * (MI * 16) + mi * 16 + lr;
                af[mi] = ldfrag(&sA[(row * 8 + ((s * 4 + lq) ^ (row & 7))) * 8]);
            }
#pragma unroll
            for (int ni = 0; ni < 4; ni++) {
                int row = wn * 64 + ni * 16 + lr;
                bfr[ni] = ldfrag(&sB[(row * 8 + ((s * 4 + lq) ^ (row & 7))) * 8]);
            }
#pragma unroll
            for (int mi = 0; mi < MI; mi++)
#pragma unroll
                for (int ni = 0; ni < 4; ni++)
                    acc[mi][ni] = MFMA16(af[mi], bfr[ni], acc[mi][ni]);
        }
    }

    const float lamf = lam[0];
#pragma unroll
    for (int mi = 0; mi < MI; mi++)
#pragma unroll
        for (int ni = 0; ni < 4; ni++) {
            int mb = m0 + wm * (MI * 16) + mi * 16 + lq * 4;
            int n  = n0 + wn * 64 + ni * 16 + lr;
            float bv = bias[n];
            if (mode == 3) {
#pragma unroll
                for (int r = 0; r < 4; r++)
                    out[(size_t)(mb + r) * EMB + n] = acc[mi][ni][r] + bv;
            } else {
                int b = mb >> 11, s0 = mb & 2047;
                int h = n >> 6,  d = n & 63;
                if (mode == 0) {
#pragma unroll
                    for (int r = 0; r < 4; r++) {
                        float val = acc[mi][ni][r] + bv;
                        size_t i128 = ((size_t)(b * NH + h) * SEQ + s0 + r) * 128 + d;
                        Qa[i128]      = f2b(val * (0.125f * LOG2E));
                        Qa[i128 + 64] = f2b(lamf * LOG2E * fast_tanh(val));
                    }
                } else if (mode == 1) {
#pragma unroll
                    for (int r = 0; r < 4; r++) {
                        float val = acc[mi][ni][r] + bv;
                        Ka[((size_t)(b * NH + h) * SEQ + s0 + r) * 128 + d] = f2b(val);
                    }
                } else {
                    u16x4 pk = pack4(acc[mi][ni][0] + bv, acc[mi][ni][1] + bv,
                                     acc[mi][ni][2] + bv, acc[mi][ni][3] + bv);
                    *(u16x4*)&Vt[((size_t)(b * NH + h) * HD + d) * SEQ + s0] = pk;
                }
            }
        }
}

// ---------------------------------------------------------------------------
// U kernel: Ka[:,64:128] = tanh(K) @ J_h^T per (b,h); K read from Ka[:,0:64]
// grid: (S/64, B*H), 256 threads
// ---------------------------------------------------------------------------
__global__ __launch_bounds__(256) void ukern(
        const float* __restrict__ J, u16* __restrict__ Ka)
{
    __shared__ __attribute__((aligned(16))) u16 sJ[64 * 72];
    const int t = threadIdx.x, w = t >> 6, L = t & 63, lr = L & 15, lq = L >> 4;
    const int rt = blockIdx.x, bh = blockIdx.y, h = bh & 15;

#pragma unroll
    for (int i = 0; i < 2; i++) {
        int c = t + 256 * i;
        int row = c >> 3, col = (c & 7) * 8;
        *(bf16x8*)&sJ[row * 72 + col] = cvt8(&J[(size_t)h * 4096 + row * 64 + col]);
    }
    __syncthreads();

    const u16* krow = &Ka[((size_t)bh * SEQ + rt * 64 + w * 16 + lr) * 128];
    bf16x8 a0 = tanh8(ldfrag(krow + lq * 8));
    bf16x8 a1 = tanh8(ldfrag(krow + lq * 8 + 32));
#pragma unroll
    for (int nt = 0; nt < 4; nt++) {
        f32x4 acc = {0.f, 0.f, 0.f, 0.f};
        acc = MFMA16(a0, ldfrag(&sJ[(nt * 16 + lr) * 72 + lq * 8]), acc);
        acc = MFMA16(a1, ldfrag(&sJ[(nt * 16 + lr) * 72 + lq * 8 + 32]), acc);
#pragma unroll
        for (int r = 0; r < 4; r++) {
            int j = rt * 64 + w * 16 + lq * 4 + r;
            Ka[((size_t)bh * SEQ + j) * 128 + 64 + nt * 16 + lr] = f2b(acc[r]);
        }
    }
}

// ---------------------------------------------------------------------------
// Causal flash, S^T formulation, BM=128: each wave holds TWO 16-row Q B-operand
// sets in regs, so every K/V A-fragment read from LDS feeds 2 MFMAs.
// ROUND 1: double-buffered K/V staging — prefetch tile t+1 is issued BEFORE
// compute of tile t; ONE __syncthreads per tile (its implicit vmcnt(0) is the
// prefetch wait, paid after compute instead of before). Removes the exposed
// per-tile load latency that held MfmaUtil at 16%. Hazard note: the buffer
// staged at tile t is the compute buffer of t-1; its ds_reads complete before
// t-1's MFMAs, hence before the end-of-(t-1) barrier -> single barrier safe.
// sP rows are wave-private (same wave writes+reads) -> no barrier needed.
// LDS 43KB -> 66KB, still 2 blocks/CU (grid gives exactly 2/CU anyway).
// grid: (256, 2): bh = bx&31 (XCD-local), p = bx>>5; qt = by? 15-p : p
// ---------------------------------------------------------------------------
__global__ __launch_bounds__(256) void flash(
        const u16* __restrict__ Qa, const u16* __restrict__ Ka,
        const u16* __restrict__ Vt, u16* __restrict__ attn)
{
    __shared__ __attribute__((aligned(16))) u16 sK[2][64 * 128];   // swizzled chunks
    __shared__ __attribute__((aligned(16))) u16 sVt[2][64 * 64];   // swizzled chunks
    __shared__ __attribute__((aligned(16))) u16 sP[128 * 72];      // padded rows

    const int t = threadIdx.x, w = t >> 6, L = t & 63, lr = L & 15, lq = L >> 4;
    const int bh = blockIdx.x & 31, p = blockIdx.x >> 5;
    const int qt = blockIdx.y ? 15 - p : p;
    const int qm = qt * 128;
    const int i_l = w * 16 + lr;            // lane's q-row within a 64-set
    const int wbase = t & 192;
    const u16* Kbase = Ka + (size_t)bh * SEQ * 128;
    const u16* Vbase = Vt + (size_t)bh * HD * SEQ;

    // two Q B-operand sets: set g covers q-rows qm + g*64 + [0,64)
    bf16x8 qf[2][4];
#pragma unroll
    for (int g = 0; g < 2; g++) {
        const u16* qrow = Qa + ((size_t)bh * SEQ + qm + g * 64 + i_l) * 128;
#pragma unroll
        for (int s = 0; s < 4; s++) qf[g][s] = ldfrag(qrow + s * 32 + lq * 8);
    }

    f32x4 Ot[2][4];
#pragma unroll
    for (int g = 0; g < 2; g++)
#pragma unroll
        for (int i = 0; i < 4; i++) { f32x4 z = {0.f, 0.f, 0.f, 0.f}; Ot[g][i] = z; }
    float lsum[2] = {0.f, 0.f};

    const int ktmax = 2 * qt + 1;

    // stage K tile 64x128 (swizzle col8 = cc ^ (row&15)) + V^T tile 64x64
    // (swizzle j8 = cc ^ (d&7)) into buffer bsel: 6 global_load_lds per lane
    auto stage = [&](int kt, int bsel) {
        const int kn = kt * 64;
#pragma unroll
        for (int q = 0; q < 4; q++) {
            int cch = q * 256 + t;
            int row = cch >> 4, cc = cch & 15;
            int col8 = cc ^ (row & 15);
            GLOAD_LDS16(&Kbase[(size_t)(kn + row) * 128 + col8 * 8],
                        &sK[bsel][(q * 256 + wbase) * 8]);
        }
#pragma unroll
        for (int q = 0; q < 2; q++) {
            int cch = q * 256 + t;
            int d = cch >> 3, cc = cch & 7;
            int j8 = cc ^ (d & 7);
            GLOAD_LDS16(&Vbase[(size_t)d * SEQ + kn + j8 * 8],
                        &sVt[bsel][(q * 256 + wbase) * 8]);
        }
    };

    stage(0, 0);
    __syncthreads();          // vmcnt(0): tile 0 resident

    int cur = 0;
    for (int kt = 0; kt <= ktmax; kt++) {
        if (kt < ktmax) stage(kt + 1, cur ^ 1);   // prefetch: latency hides under compute
        const u16* sKc = sK[cur];
        const u16* sVc = sVt[cur];

        // S^T: each K-fragment feeds both Q sets
        f32x4 sc[2][4];
#pragma unroll
        for (int g = 0; g < 2; g++)
#pragma unroll
            for (int mt = 0; mt < 4; mt++) { f32x4 z = {0.f,0.f,0.f,0.f}; sc[g][mt] = z; }
        __builtin_amdgcn_s_setprio(1);
#pragma unroll
        for (int mt = 0; mt < 4; mt++) {
            int j = mt * 16 + lr;
#pragma unroll
            for (int s = 0; s < 4; s++) {
                bf16x8 kf = ldfrag(&sKc[(j * 16 + ((s * 4 + lq) ^ (j & 15))) * 8]);
                sc[0][mt] = MFMA16(kf, qf[0][s], sc[0][mt]);
                sc[1][mt] = MFMA16(kf, qf[1][s], sc[1][mt]);
            }
        }
        __builtin_amdgcn_s_setprio(0);
        // causal masks only on the last two k-tiles
        if (kt >= ktmax - 1) {
            const int thr0 = (kt == ktmax) ? -1  : i_l;
            const int thr1 = (kt == ktmax) ? i_l : 63;
#pragma unroll
            for (int mt = 0; mt < 4; mt++)
#pragma unroll
                for (int r = 0; r < 4; r++) {
                    int j = mt * 16 + lq * 4 + r;
                    if (j > thr0) sc[0][mt][r] = -INFINITY;
                    if (j > thr1) sc[1][mt][r] = -INFINITY;
                }
        }
        // no-max softmax: P = exp2(s); raw v_exp_f32 (exp2(-inf)=0 for masked)
#pragma unroll
        for (int g = 0; g < 2; g++) {
#pragma unroll
            for (int mt = 0; mt < 4; mt++)
#pragma unroll
                for (int r = 0; r < 4; r++) {
                    float e = __builtin_amdgcn_exp2f(sc[g][mt][r]);
                    sc[g][mt][r] = e;
                    lsum[g] += e;
                }
#pragma unroll
            for (int mt = 0; mt < 4; mt++)
                *(u16x4*)&sP[(g * 64 + i_l) * 72 + mt * 16 + lq * 4] =
                    pack4(sc[g][mt][0], sc[g][mt][1], sc[g][mt][2], sc[g][mt][3]);
        }
        // O^T += V^T @ P^T: each V-fragment feeds both P sets
        __builtin_amdgcn_s_setprio(1);
#pragma unroll
        for (int s2 = 0; s2 < 2; s2++) {
            bf16x8 pf0 = ldfrag(&sP[(i_l) * 72 + s2 * 32 + lq * 8]);
            bf16x8 pf1 = ldfrag(&sP[(64 + i_l) * 72 + s2 * 32 + lq * 8]);
#pragma unroll
            for (int mt = 0; mt < 4; mt++) {
                int d = mt * 16 + lr;
                bf16x8 vf = ldfrag(&sVc[(d * 8 + ((s2 * 4 + lq) ^ (d & 7))) * 8]);
                Ot[0][mt] = MFMA16(vf, pf0, Ot[0][mt]);
                Ot[1][mt] = MFMA16(vf, pf1, Ot[1][mt]);
            }
        }
        __builtin_amdgcn_s_setprio(0);
        __syncthreads();      // vmcnt(0): prefetched tile resident; buffers swappable
        cur ^= 1;
    }

    const int b = bh >> 4, h = bh & 15;
#pragma unroll
    for (int g = 0; g < 2; g++) {
        float ls = lsum[g];
        ls += __shfl_xor(ls, 16);
        ls += __shfl_xor(ls, 32);
        const float r0 = __builtin_amdgcn_rcpf(ls);
        const float inv = r0 * (2.0f - ls * r0);  // NR refine
        const size_t base = ((size_t)(b * SEQ + qm + g * 64 + i_l)) * EMB + h * HD;
#pragma unroll
        for (int mt = 0; mt < 4; mt++)
            *(u16x4*)&attn[base + mt * 16 + lq * 4] =
                pack4(Ot[g][mt][0] * inv, Ot[g][mt][1] * inv,
                      Ot[g][mt][2] * inv, Ot[g][mt][3] * inv);
    }
}

// ---------------------------------------------------------------------------
extern "C" void kernel_launch(void* const* d_in, const int* in_sizes, int n_in,
                              void* d_out, int out_size, void* d_ws, size_t ws_size,
                              hipStream_t stream)
{
    const float* x   = (const float*)d_in[0];
    const float* Wq  = (const float*)d_in[1];
    const float* bq  = (const float*)d_in[2];
    const float* Wk  = (const float*)d_in[3];
    const float* bk  = (const float*)d_in[4];
    const float* Wv  = (const float*)d_in[5];
    const float* bv  = (const float*)d_in[6];
    const float* Wo  = (const float*)d_in[7];
    const float* bo  = (const float*)d_in[8];
    const float* J   = (const float*)d_in[9];
    const float* lam = (const float*)d_in[10];

    u16* ws  = (u16*)d_ws;
    u16* xb  = ws;                                   // 4096*1024 bf16 (reused as attn)
    u16* Wqb = xb  + (size_t)4096 * 1024;
    u16* Wkb = Wqb + (size_t)1024 * 1024;
    u16* Wvb = Wkb + (size_t)1024 * 1024;
    u16* Wob = Wvb + (size_t)1024 * 1024;
    u16* Qa  = Wob + (size_t)1024 * 1024;            // 32*2048*128
    u16* Ka  = Qa  + (size_t)32 * 2048 * 128;        // 32*2048*128
    u16* Vt  = Ka  + (size_t)32 * 2048 * 128;        // 32*64*2048 (b,h,d,s)
    u16* attn = xb;                                  // alias: xb dead after QKV
    float* dout = (float*)d_out;

    dim3 blk(256);
    // fp32 -> bf16 for x and the four weight matrices
    cvt_all<<<dim3(4096), blk, 0, stream>>>(x, Wq, Wk, Wv, Wo, ws);
    // fused Q/K/V projections (BK=64)
    gemm_epi<4><<<dim3(8, 32, 3), blk, 0, stream>>>(
        xb, Wqb, bq, Wkb, bk, Wvb, bv, lam, Qa, Ka, Vt, dout, 0);
    // Ka[:,64:128] = tanh(K) @ J_h^T
    ukern<<<dim3(32, 32), blk, 0, stream>>>(J, Ka);
    // causal flash attention, BM=128, augmented 128-dim QK
    flash<<<dim3(256, 2), blk, 0, stream>>>(Qa, Ka, Vt, attn);
    // output projection (64-row tiles -> 512 blocks for occupancy)
    gemm_epi<2><<<dim3(8, 64, 1), blk, 0, stream>>>(
        attn, Wob, bo, Wob, bo, Wob, bo, lam, Qa, Ka, Vt, dout, 3);
}

// Round 2
// 196.712 us; speedup vs baseline: 1.0846x; 1.0517x over previous
//
#include <hip/hip_runtime.h>
#include <hip/hip_bf16.h>

typedef unsigned short u16;
typedef __bf16 bf16x8 __attribute__((ext_vector_type(8)));
typedef float f32x4 __attribute__((ext_vector_type(4)));
typedef unsigned short u16x4 __attribute__((ext_vector_type(4)));

#define MFMA16(a, b, c) __builtin_amdgcn_mfma_f32_16x16x32_bf16(a, b, c, 0, 0, 0)

#define EMB 1024
#define SEQ 2048
#define NH 16
#define HD 64
#define LOG2E 1.4426950408889634f

// async global->LDS, 16B per lane; LDS dest = wave-uniform base + lane*16
#define GLOAD_LDS16(g, l) __builtin_amdgcn_global_load_lds( \
    (const __attribute__((address_space(1))) unsigned int*)(g), \
    (__attribute__((address_space(3))) unsigned int*)(l), 16, 0, 0)

__device__ __forceinline__ float b2f(u16 u) {
    union { unsigned int i; float f; } v; v.i = ((unsigned int)u) << 16; return v.f;
}
__device__ __forceinline__ u16 f2b(float f) {
    __hip_bfloat16 h = __float2bfloat16(f);
    return *reinterpret_cast<u16*>(&h);
}
__device__ __forceinline__ u16x4 pack4(float a, float b, float c, float d) {
    union { __hip_bfloat162 h2[2]; u16x4 u; } r;
    r.h2[0] = __float22bfloat162_rn(float2{a, b});
    r.h2[1] = __float22bfloat162_rn(float2{c, d});
    return r.u;
}
__device__ __forceinline__ bf16x8 ldfrag(const u16* p) {
    return *reinterpret_cast<const bf16x8*>(p);
}
__device__ __forceinline__ bf16x8 cvt8(const float* p) {
    const float4 a = *reinterpret_cast<const float4*>(p);
    const float4 b = *reinterpret_cast<const float4*>(p + 4);
    union { u16x4 q[2]; bf16x8 v; } r;
    r.q[0] = pack4(a.x, a.y, a.z, a.w);
    r.q[1] = pack4(b.x, b.y, b.z, b.w);
    return r.v;
}
// tanh via hw exp2 + rcp: rel err < 1e-6, safe for |x| < 40
__device__ __forceinline__ float fast_tanh(float x) {
    float t = __builtin_amdgcn_exp2f(x * (2.0f * LOG2E));
    return 1.0f - 2.0f * __builtin_amdgcn_rcpf(t + 1.0f);
}
__device__ __forceinline__ bf16x8 tanh8(bf16x8 v) {
    union { bf16x8 v; u16 u[8]; } in; in.v = v;
    float o[8];
#pragma unroll
    for (int e = 0; e < 8; e++) o[e] = fast_tanh(b2f(in.u[e]));
    union { u16x4 q[2]; bf16x8 v; } r;
    r.q[0] = pack4(o[0], o[1], o[2], o[3]);
    r.q[1] = pack4(o[4], o[5], o[6], o[7]);
    return r.v;
}

// ---------------------------------------------------------------------------
// fp32 -> bf16 conversion: [x (4096x1024) | Wq | Wk | Wv | Wo] -> ws bf16
// ---------------------------------------------------------------------------
__global__ __launch_bounds__(256) void cvt_all(
        const float* __restrict__ x,  const float* __restrict__ Wq,
        const float* __restrict__ Wk, const float* __restrict__ Wv,
        const float* __restrict__ Wo, u16* __restrict__ dst)
{
    size_t i = ((size_t)blockIdx.x * 256 + threadIdx.x) * 8;
    const float* src; size_t off;
    if (i < 4194304) { src = x; off = i; }
    else {
        size_t j = i - 4194304; int w = (int)(j >> 20); off = j & 1048575;
        src = (w == 0) ? Wq : (w == 1) ? Wk : (w == 2) ? Wv : Wo;
    }
    *(bf16x8*)&dst[i] = cvt8(src + off);
}

// ---------------------------------------------------------------------------
// GEMM: C = A(MxK,bf16) @ W(NxK,bf16)^T + bias(fp32). Tile MI*32 x 128, BK=64.
// ---------------------------------------------------------------------------
template<int MI>   // m-frags per wave (4 -> 128-row tile, 2 -> 64-row tile)
__global__ __launch_bounds__(256, 4) void gemm_epi(
        const u16* __restrict__ A,
        const u16* __restrict__ W0, const float* __restrict__ B0,
        const u16* __restrict__ W1, const float* __restrict__ B1,
        const u16* __restrict__ W2, const float* __restrict__ B2,
        const float* __restrict__ lam,
        u16* __restrict__ Qa, u16* __restrict__ Ka, u16* __restrict__ Vt,
        float* __restrict__ out, int modeBase)
{
    const int mode = modeBase + blockIdx.z;
    const u16* W; const float* bias;
    if (blockIdx.z == 0)      { W = W0; bias = B0; }
    else if (blockIdx.z == 1) { W = W1; bias = B1; }
    else                      { W = W2; bias = B2; }

    __shared__ __attribute__((aligned(16))) u16 sA[MI * 32 * 64];
    __shared__ __attribute__((aligned(16))) u16 sB[128 * 64];

    const int t = threadIdx.x;
    const int w = t >> 6, L = t & 63;
    const int wm = w >> 1, wn = w & 1;
    const int lr = L & 15, lq = L >> 4;
    const int wbase = t & 192;                   // wave*64
    const int m0 = blockIdx.y * (MI * 32), n0 = blockIdx.x * 128;

    f32x4 acc[MI][4];
#pragma unroll
    for (int i = 0; i < MI; i++)
#pragma unroll
        for (int j = 0; j < 4; j++) { f32x4 z = {0.f, 0.f, 0.f, 0.f}; acc[i][j] = z; }

    for (int k0 = 0; k0 < EMB; k0 += 64) {
        __syncthreads();
        // stage A: MI*256 chunks of 8 elems (8 chunks/row), col8 = cc ^ (row&7)
#pragma unroll
        for (int q = 0; q < MI; q++) {
            int c = q * 256 + t;
            int row = c >> 3, cc = c & 7;
            int col8 = cc ^ (row & 7);
            GLOAD_LDS16(&A[(size_t)(m0 + row) * EMB + k0 + col8 * 8],
                        &sA[(q * 256 + wbase) * 8]);
        }
        // stage B: 1024 chunks
#pragma unroll
        for (int q = 0; q < 4; q++) {
            int c = q * 256 + t;
            int row = c >> 3, cc = c & 7;
            int col8 = cc ^ (row & 7);
            GLOAD_LDS16(&W[(size_t)(n0 + row) * EMB + k0 + col8 * 8],
                        &sB[(q * 256 + wbase) * 8]);
        }
        __syncthreads();
        // two 32-k sub-chunks; fragments loaded per sub-chunk to bound VGPR
#pragma unroll
        for (int s = 0; s < 2; s++) {
            bf16x8 af[MI], bfr[4];
#pragma unroll
            for (int mi = 0; mi < MI; mi++) {
                int row = wm * (MI * 16) + mi * 16 + lr;
                af[mi] = ldfrag(&sA[(row * 8 + ((s * 4 + lq) ^ (row & 7))) * 8]);
            }
#pragma unroll
            for (int ni = 0; ni < 4; ni++) {
                int row = wn * 64 + ni * 16 + lr;
                bfr[ni] = ldfrag(&sB[(row * 8 + ((s * 4 + lq) ^ (row & 7))) * 8]);
            }
#pragma unroll
            for (int mi = 0; mi < MI; mi++)
#pragma unroll
                for (int ni = 0; ni < 4; ni++)
                    acc[mi][ni] = MFMA16(af[mi], bfr[ni], acc[mi][ni]);
        }
    }

    const float lamf = lam[0];
#pragma unroll
    for (int mi = 0; mi < MI; mi++)
#pragma unroll
        for (int ni = 0; ni < 4; ni++) {
            int mb = m0 + wm * (MI * 16) + mi * 16 + lq * 4;
            int n  = n0 + wn * 64 + ni * 16 + lr;
            float bv = bias[n];
            if (mode == 3) {
#pragma unroll
                for (int r = 0; r < 4; r++)
                    out[(size_t)(mb + r) * EMB + n] = acc[mi][ni][r] + bv;
            } else {
                int b = mb >> 11, s0 = mb & 2047;
                int h = n >> 6,  d = n & 63;
                if (mode == 0) {
#pragma unroll
                    for (int r = 0; r < 4; r++) {
                        float val = acc[mi][ni][r] + bv;
                        size_t i128 = ((size_t)(b * NH + h) * SEQ + s0 + r) * 128 + d;
                        Qa[i128]      = f2b(val * (0.125f * LOG2E));
                        Qa[i128 + 64] = f2b(lamf * LOG2E * fast_tanh(val));
                    }
                } else if (mode == 1) {
#pragma unroll
                    for (int r = 0; r < 4; r++) {
                        float val = acc[mi][ni][r] + bv;
                        Ka[((size_t)(b * NH + h) * SEQ + s0 + r) * 128 + d] = f2b(val);
                    }
                } else {
                    u16x4 pk = pack4(acc[mi][ni][0] + bv, acc[mi][ni][1] + bv,
                                     acc[mi][ni][2] + bv, acc[mi][ni][3] + bv);
                    *(u16x4*)&Vt[((size_t)(b * NH + h) * HD + d) * SEQ + s0] = pk;
                }
            }
        }
}

// ---------------------------------------------------------------------------
// U kernel: Ka[:,64:128] = tanh(K) @ J_h^T per (b,h); K read from Ka[:,0:64]
// grid: (S/64, B*H), 256 threads
// ---------------------------------------------------------------------------
__global__ __launch_bounds__(256) void ukern(
        const float* __restrict__ J, u16* __restrict__ Ka)
{
    __shared__ __attribute__((aligned(16))) u16 sJ[64 * 72];
    const int t = threadIdx.x, w = t >> 6, L = t & 63, lr = L & 15, lq = L >> 4;
    const int rt = blockIdx.x, bh = blockIdx.y, h = bh & 15;

#pragma unroll
    for (int i = 0; i < 2; i++) {
        int c = t + 256 * i;
        int row = c >> 3, col = (c & 7) * 8;
        *(bf16x8*)&sJ[row * 72 + col] = cvt8(&J[(size_t)h * 4096 + row * 64 + col]);
    }
    __syncthreads();

    const u16* krow = &Ka[((size_t)bh * SEQ + rt * 64 + w * 16 + lr) * 128];
    bf16x8 a0 = tanh8(ldfrag(krow + lq * 8));
    bf16x8 a1 = tanh8(ldfrag(krow + lq * 8 + 32));
#pragma unroll
    for (int nt = 0; nt < 4; nt++) {
        f32x4 acc = {0.f, 0.f, 0.f, 0.f};
        acc = MFMA16(a0, ldfrag(&sJ[(nt * 16 + lr) * 72 + lq * 8]), acc);
        acc = MFMA16(a1, ldfrag(&sJ[(nt * 16 + lr) * 72 + lq * 8 + 32]), acc);
#pragma unroll
        for (int r = 0; r < 4; r++) {
            int j = rt * 64 + w * 16 + lq * 4 + r;
            Ka[((size_t)bh * SEQ + j) * 128 + 64 + nt * 16 + lr] = f2b(acc[r]);
        }
    }
}

// ---------------------------------------------------------------------------
// Causal flash, S^T formulation, BM=128.
// ROUND 2: load-balance fix. Old grid (512 blk x 4 waves) paired (qt=p,
// qt=15-p) per CU but the light partner exits early -> half the dispatch runs
// 1 wave/SIMD (OccupancyPercent 11.6% vs 25% cap). Now: 256 blocks x 512 thr
// (8 waves), each block processes qt=p THEN qt=15-p sequentially = exactly 34
// k-tiles per block (uniform, zero tail), 8 waves/CU sustained. The 8 waves
// split each k-tile in half (wk = w>>2): group wk owns S^T k-cols
// [wk*32,wk*32+32) (mt = wk*2+{0,1}) and PV k-fragment s2 = wk. Each wave
// keeps TWO 16-row Q B-operand sets (every kf LDS read feeds 2 MFMAs). P
// stays wave-private in sP. Partial Ot/lsum (k-split) combined per segment
// via LDS (sK reused as f32 buffer after the final barrier).
// Keeps: K/V double-buffer w/ 1 barrier/tile, setprio around MFMA, raw exp2.
// grid: (256): bh = bx&31 (all 8 p-blocks of a bh land on one XCD), p = bx>>5
// ---------------------------------------------------------------------------
__global__ __launch_bounds__(512) void flash(
        const u16* __restrict__ Qa, const u16* __restrict__ Ka,
        const u16* __restrict__ Vt, u16* __restrict__ attn)
{
    __shared__ __attribute__((aligned(16))) u16 sK[2][64 * 128];   // 32 KB
    __shared__ __attribute__((aligned(16))) u16 sVt[2][64 * 64];   // 16 KB
    __shared__ __attribute__((aligned(16))) u16 sP[128 * 72];      // 18 KB
    __shared__ float sLs[2][4][64][2];                             // 4 KB

    const int t = threadIdx.x, w = t >> 6, L = t & 63, lr = L & 15, lq = L >> 4;
    const int wq = w & 3, wk = w >> 2;
    const int bh = blockIdx.x & 31, p = blockIdx.x >> 5;
    const int i_l = wq * 16 + lr;           // lane's q-row within a 64-set
    const int wbase = t & 448;              // w*64
    const u16* Kbase = Ka + (size_t)bh * SEQ * 128;
    const u16* Vbase = Vt + (size_t)bh * HD * SEQ;
    const int b = bh >> 4, h = bh & 15;
    float* sOt = reinterpret_cast<float*>(sK);   // 32 KB combine buffer

    // stage K tile 64x128 (swizzle col8 = cc ^ (row&15)) + V^T tile 64x64
    // (swizzle j8 = cc ^ (d&7)): 3 global_load_lds per lane (512 thr)
    auto stage = [&](int kn, int bsel) {
#pragma unroll
        for (int q = 0; q < 2; q++) {
            int cch = q * 512 + t;
            int row = cch >> 4, cc = cch & 15;
            int col8 = cc ^ (row & 15);
            GLOAD_LDS16(&Kbase[(size_t)(kn + row) * 128 + col8 * 8],
                        &sK[bsel][(q * 512 + wbase) * 8]);
        }
        {
            int d = t >> 3, cc = t & 7;
            int j8 = cc ^ (d & 7);
            GLOAD_LDS16(&Vbase[(size_t)d * SEQ + kn + j8 * 8],
                        &sVt[bsel][wbase * 8]);
        }
    };

#pragma unroll 1
    for (int seg = 0; seg < 2; seg++) {
        const int qt = seg ? 15 - p : p;
        const int qm = qt * 128;
        const int ktmax = 2 * qt + 1;

        // two Q B-operand sets: set g covers q-rows qm + g*64 + [0,64)
        bf16x8 qf[2][4];
#pragma unroll
        for (int g = 0; g < 2; g++) {
            const u16* qrow = Qa + ((size_t)bh * SEQ + qm + g * 64 + i_l) * 128;
#pragma unroll
            for (int s = 0; s < 4; s++) qf[g][s] = ldfrag(qrow + s * 32 + lq * 8);
        }

        f32x4 Ot[2][4];
#pragma unroll
        for (int g = 0; g < 2; g++)
#pragma unroll
            for (int i = 0; i < 4; i++) { f32x4 z = {0.f, 0.f, 0.f, 0.f}; Ot[g][i] = z; }
        float lsum[2] = {0.f, 0.f};

        stage(0, 0);
        __syncthreads();          // vmcnt(0): tile 0 resident

        int cur = 0;
        for (int kt = 0; kt <= ktmax; kt++) {
            if (kt < ktmax) stage((kt + 1) * 64, cur ^ 1);  // prefetch under compute
            const u16* sKc = sK[cur];
            const u16* sVc = sVt[cur];

            // S^T: group wk owns k-cols [wk*32, wk*32+32); each kf feeds 2 Q sets
            f32x4 sc[2][2];
#pragma unroll
            for (int g = 0; g < 2; g++)
#pragma unroll
                for (int m = 0; m < 2; m++) { f32x4 z = {0.f,0.f,0.f,0.f}; sc[g][m] = z; }
            __builtin_amdgcn_s_setprio(1);
#pragma unroll
            for (int mt2 = 0; mt2 < 2; mt2++) {
                int j = (wk * 2 + mt2) * 16 + lr;
#pragma unroll
                for (int s = 0; s < 4; s++) {
                    bf16x8 kf = ldfrag(&sKc[(j * 16 + ((s * 4 + lq) ^ (j & 15))) * 8]);
                    sc[0][mt2] = MFMA16(kf, qf[0][s], sc[0][mt2]);
                    sc[1][mt2] = MFMA16(kf, qf[1][s], sc[1][mt2]);
                }
            }
            __builtin_amdgcn_s_setprio(0);
            // causal masks only on the last two k-tiles
            if (kt >= ktmax - 1) {
                const int thr0 = (kt == ktmax) ? -1  : i_l;
                const int thr1 = (kt == ktmax) ? i_l : 63;
#pragma unroll
                for (int mt2 = 0; mt2 < 2; mt2++)
#pragma unroll
                    for (int r = 0; r < 4; r++) {
                        int j = (wk * 2 + mt2) * 16 + lq * 4 + r;
                        if (j > thr0) sc[0][mt2][r] = -INFINITY;
                        if (j > thr1) sc[1][mt2][r] = -INFINITY;
                    }
            }
            // no-max softmax: P = exp2(s); raw v_exp_f32 (exp2(-inf)=0 masked)
#pragma unroll
            for (int g = 0; g < 2; g++) {
#pragma unroll
                for (int mt2 = 0; mt2 < 2; mt2++) {
#pragma unroll
                    for (int r = 0; r < 4; r++) {
                        float e = __builtin_amdgcn_exp2f(sc[g][mt2][r]);
                        sc[g][mt2][r] = e;
                        lsum[g] += e;
                    }
                    *(u16x4*)&sP[(g * 64 + i_l) * 72 + (wk * 2 + mt2) * 16 + lq * 4] =
                        pack4(sc[g][mt2][0], sc[g][mt2][1], sc[g][mt2][2], sc[g][mt2][3]);
                }
            }
            // O^T += V^T @ P^T over this group's k-fragment (s2 = wk)
            __builtin_amdgcn_s_setprio(1);
            {
                bf16x8 pf0 = ldfrag(&sP[(i_l) * 72 + wk * 32 + lq * 8]);
                bf16x8 pf1 = ldfrag(&sP[(64 + i_l) * 72 + wk * 32 + lq * 8]);
#pragma unroll
                for (int mt = 0; mt < 4; mt++) {
                    int d = mt * 16 + lr;
                    bf16x8 vf = ldfrag(&sVc[(d * 8 + ((wk * 4 + lq) ^ (d & 7))) * 8]);
                    Ot[0][mt] = MFMA16(vf, pf0, Ot[0][mt]);
                    Ot[1][mt] = MFMA16(vf, pf1, Ot[1][mt]);
                }
            }
            __builtin_amdgcn_s_setprio(0);
            __syncthreads();      // vmcnt(0): prefetched tile resident
            cur ^= 1;
        }

        // ---- combine k-split partials and write this segment's output ----
#pragma unroll
        for (int g = 0; g < 2; g++) {
            lsum[g] += __shfl_xor(lsum[g], 16);
            lsum[g] += __shfl_xor(lsum[g], 32);
            sLs[wk][wq][L][g] = lsum[g];
        }
        if (wk == 1) {
            float* dst = &sOt[((size_t)wq * 64 + L) * 32];
#pragma unroll
            for (int g = 0; g < 2; g++)
#pragma unroll
                for (int mt = 0; mt < 4; mt++)
#pragma unroll
                    for (int r = 0; r < 4; r++)
                        dst[g * 16 + mt * 4 + r] = Ot[g][mt][r];
        }
        __syncthreads();
        if (wk == 0) {
            const float* src = &sOt[((size_t)wq * 64 + L) * 32];
#pragma unroll
            for (int g = 0; g < 2; g++) {
                float ls = lsum[g] + sLs[1][wq][L][g];
                const float r0 = __builtin_amdgcn_rcpf(ls);
                const float inv = r0 * (2.0f - ls * r0);  // NR refine
                const size_t base =
                    ((size_t)(b * SEQ + qm + g * 64 + i_l)) * EMB + h * HD;
#pragma unroll
                for (int mt = 0; mt < 4; mt++)
                    *(u16x4*)&attn[base + mt * 16 + lq * 4] = pack4(
                        (Ot[g][mt][0] + src[g * 16 + mt * 4 + 0]) * inv,
                        (Ot[g][mt][1] + src[g * 16 + mt * 4 + 1]) * inv,
                        (Ot[g][mt][2] + src[g * 16 + mt * 4 + 2]) * inv,
                        (Ot[g][mt][3] + src[g * 16 + mt * 4 + 3]) * inv);
            }
        }
        __syncthreads();   // protect sOt/sLs before next segment's staging
    }
}

// ---------------------------------------------------------------------------
extern "C" void kernel_launch(void* const* d_in, const int* in_sizes, int n_in,
                              void* d_out, int out_size, void* d_ws, size_t ws_size,
                              hipStream_t stream)
{
    const float* x   = (const float*)d_in[0];
    const float* Wq  = (const float*)d_in[1];
    const float* bq  = (const float*)d_in[2];
    const float* Wk  = (const float*)d_in[3];
    const float* bk  = (const float*)d_in[4];
    const float* Wv  = (const float*)d_in[5];
    const float* bv  = (const float*)d_in[6];
    const float* Wo  = (const float*)d_in[7];
    const float* bo  = (const float*)d_in[8];
    const float* J   = (const float*)d_in[9];
    const float* lam = (const float*)d_in[10];

    u16* ws  = (u16*)d_ws;
    u16* xb  = ws;                                   // 4096*1024 bf16 (reused as attn)
    u16* Wqb = xb  + (size_t)4096 * 1024;
    u16* Wkb = Wqb + (size_t)1024 * 1024;
    u16* Wvb = Wkb + (size_t)1024 * 1024;
    u16* Wob = Wvb + (size_t)1024 * 1024;
    u16* Qa  = Wob + (size_t)1024 * 1024;            // 32*2048*128
    u16* Ka  = Qa  + (size_t)32 * 2048 * 128;        // 32*2048*128
    u16* Vt  = Ka  + (size_t)32 * 2048 * 128;        // 32*64*2048 (b,h,d,s)
    u16* attn = xb;                                  // alias: xb dead after QKV
    float* dout = (float*)d_out;

    dim3 blk(256);
    // fp32 -> bf16 for x and the four weight matrices
    cvt_all<<<dim3(4096), blk, 0, stream>>>(x, Wq, Wk, Wv, Wo, ws);
    // fused Q/K/V projections (BK=64)
    gemm_epi<4><<<dim3(8, 32, 3), blk, 0, stream>>>(
        xb, Wqb, bq, Wkb, bk, Wvb, bv, lam, Qa, Ka, Vt, dout, 0);
    // Ka[:,64:128] = tanh(K) @ J_h^T
    ukern<<<dim3(32, 32), blk, 0, stream>>>(J, Ka);
    // causal flash attention: 256 blocks x 512 thr, qt pair (p, 15-p) per block
    flash<<<dim3(256), dim3(512), 0, stream>>>(Qa, Ka, Vt, attn);
    // output projection (64-row tiles -> 512 blocks for occupancy)
    gemm_epi<2><<<dim3(8, 64, 1), blk, 0, stream>>>(
        attn, Wob, bo, Wob, bo, Wob, bo, lam, Qa, Ka, Vt, dout, 3);
}

// Round 3
// 190.772 us; speedup vs baseline: 1.1184x; 1.0311x over previous
//
#include <hip/hip_runtime.h>
#include <hip/hip_bf16.h>

typedef unsigned short u16;
typedef __bf16 bf16x8 __attribute__((ext_vector_type(8)));
typedef float f32x4 __attribute__((ext_vector_type(4)));
typedef unsigned short u16x4 __attribute__((ext_vector_type(4)));

#define MFMA16(a, b, c) __builtin_amdgcn_mfma_f32_16x16x32_bf16(a, b, c, 0, 0, 0)

#define EMB 1024
#define SEQ 2048
#define NH 16
#define HD 64
#define LOG2E 1.4426950408889634f

// async global->LDS, 16B per lane; LDS dest = wave-uniform base + lane*16
#define GLOAD_LDS16(g, l) __builtin_amdgcn_global_load_lds( \
    (const __attribute__((address_space(1))) unsigned int*)(g), \
    (__attribute__((address_space(3))) unsigned int*)(l), 16, 0, 0)

__device__ __forceinline__ float b2f(u16 u) {
    union { unsigned int i; float f; } v; v.i = ((unsigned int)u) << 16; return v.f;
}
__device__ __forceinline__ u16 f2b(float f) {
    __hip_bfloat16 h = __float2bfloat16(f);
    return *reinterpret_cast<u16*>(&h);
}
__device__ __forceinline__ u16x4 pack4(float a, float b, float c, float d) {
    union { __hip_bfloat162 h2[2]; u16x4 u; } r;
    r.h2[0] = __float22bfloat162_rn(float2{a, b});
    r.h2[1] = __float22bfloat162_rn(float2{c, d});
    return r.u;
}
__device__ __forceinline__ bf16x8 ldfrag(const u16* p) {
    return *reinterpret_cast<const bf16x8*>(p);
}
__device__ __forceinline__ bf16x8 cvt8(const float* p) {
    const float4 a = *reinterpret_cast<const float4*>(p);
    const float4 b = *reinterpret_cast<const float4*>(p + 4);
    union { u16x4 q[2]; bf16x8 v; } r;
    r.q[0] = pack4(a.x, a.y, a.z, a.w);
    r.q[1] = pack4(b.x, b.y, b.z, b.w);
    return r.v;
}
// tanh via hw exp2 + rcp: rel err < 1e-6, safe for |x| < 40
__device__ __forceinline__ float fast_tanh(float x) {
    float t = __builtin_amdgcn_exp2f(x * (2.0f * LOG2E));
    return 1.0f - 2.0f * __builtin_amdgcn_rcpf(t + 1.0f);
}
__device__ __forceinline__ bf16x8 tanh8(bf16x8 v) {
    union { bf16x8 v; u16 u[8]; } in; in.v = v;
    float o[8];
#pragma unroll
    for (int e = 0; e < 8; e++) o[e] = fast_tanh(b2f(in.u[e]));
    union { u16x4 q[2]; bf16x8 v; } r;
    r.q[0] = pack4(o[0], o[1], o[2], o[3]);
    r.q[1] = pack4(o[4], o[5], o[6], o[7]);
    return r.v;
}

// ---------------------------------------------------------------------------
// fp32 -> bf16 conversion: [x (4096x1024) | Wq | Wk | Wv | Wo] -> ws bf16
// ---------------------------------------------------------------------------
__global__ __launch_bounds__(256) void cvt_all(
        const float* __restrict__ x,  const float* __restrict__ Wq,
        const float* __restrict__ Wk, const float* __restrict__ Wv,
        const float* __restrict__ Wo, u16* __restrict__ dst)
{
    size_t i = ((size_t)blockIdx.x * 256 + threadIdx.x) * 8;
    const float* src; size_t off;
    if (i < 4194304) { src = x; off = i; }
    else {
        size_t j = i - 4194304; int w = (int)(j >> 20); off = j & 1048575;
        src = (w == 0) ? Wq : (w == 1) ? Wk : (w == 2) ? Wv : Wo;
    }
    *(bf16x8*)&dst[i] = cvt8(src + off);
}

// ---------------------------------------------------------------------------
// GEMM: C = A(MxK,bf16) @ W(NxK,bf16)^T + bias(fp32). Tile MI*32 x 128, BK=64.
// ---------------------------------------------------------------------------
template<int MI>   // m-frags per wave (4 -> 128-row tile, 2 -> 64-row tile)
__global__ __launch_bounds__(256, 4) void gemm_epi(
        const u16* __restrict__ A,
        const u16* __restrict__ W0, const float* __restrict__ B0,
        const u16* __restrict__ W1, const float* __restrict__ B1,
        const u16* __restrict__ W2, const float* __restrict__ B2,
        const float* __restrict__ lam,
        u16* __restrict__ Qa, u16* __restrict__ Ka, u16* __restrict__ Vt,
        float* __restrict__ out, int modeBase)
{
    const int mode = modeBase + blockIdx.z;
    const u16* W; const float* bias;
    if (blockIdx.z == 0)      { W = W0; bias = B0; }
    else if (blockIdx.z == 1) { W = W1; bias = B1; }
    else                      { W = W2; bias = B2; }

    __shared__ __attribute__((aligned(16))) u16 sA[MI * 32 * 64];
    __shared__ __attribute__((aligned(16))) u16 sB[128 * 64];

    const int t = threadIdx.x;
    const int w = t >> 6, L = t & 63;
    const int wm = w >> 1, wn = w & 1;
    const int lr = L & 15, lq = L >> 4;
    const int wbase = t & 192;                   // wave*64
    const int m0 = blockIdx.y * (MI * 32), n0 = blockIdx.x * 128;

    f32x4 acc[MI][4];
#pragma unroll
    for (int i = 0; i < MI; i++)
#pragma unroll
        for (int j = 0; j < 4; j++) { f32x4 z = {0.f, 0.f, 0.f, 0.f}; acc[i][j] = z; }

    for (int k0 = 0; k0 < EMB; k0 += 64) {
        __syncthreads();
        // stage A: MI*256 chunks of 8 elems (8 chunks/row), col8 = cc ^ (row&7)
#pragma unroll
        for (int q = 0; q < MI; q++) {
            int c = q * 256 + t;
            int row = c >> 3, cc = c & 7;
            int col8 = cc ^ (row & 7);
            GLOAD_LDS16(&A[(size_t)(m0 + row) * EMB + k0 + col8 * 8],
                        &sA[(q * 256 + wbase) * 8]);
        }
        // stage B: 1024 chunks
#pragma unroll
        for (int q = 0; q < 4; q++) {
            int c = q * 256 + t;
            int row = c >> 3, cc = c & 7;
            int col8 = cc ^ (row & 7);
            GLOAD_LDS16(&W[(size_t)(n0 + row) * EMB + k0 + col8 * 8],
                        &sB[(q * 256 + wbase) * 8]);
        }
        __syncthreads();
        // two 32-k sub-chunks; fragments loaded per sub-chunk to bound VGPR
#pragma unroll
        for (int s = 0; s < 2; s++) {
            bf16x8 af[MI], bfr[4];
#pragma unroll
            for (int mi = 0; mi < MI; mi++) {
                int row = wm * (MI * 16) + mi * 16 + lr;
                af[mi] = ldfrag(&sA[(row * 8 + ((s * 4 + lq) ^ (row & 7))) * 8]);
            }
#pragma unroll
            for (int ni = 0; ni < 4; ni++) {
                int row = wn * 64 + ni * 16 + lr;
                bfr[ni] = ldfrag(&sB[(row * 8 + ((s * 4 + lq) ^ (row & 7))) * 8]);
            }
#pragma unroll
            for (int mi = 0; mi < MI; mi++)
#pragma unroll
                for (int ni = 0; ni < 4; ni++)
                    acc[mi][ni] = MFMA16(af[mi], bfr[ni], acc[mi][ni]);
        }
    }

    const float lamf = lam[0];
#pragma unroll
    for (int mi = 0; mi < MI; mi++)
#pragma unroll
        for (int ni = 0; ni < 4; ni++) {
            int mb = m0 + wm * (MI * 16) + mi * 16 + lq * 4;
            int n  = n0 + wn * 64 + ni * 16 + lr;
            float bv = bias[n];
            if (mode == 3) {
#pragma unroll
                for (int r = 0; r < 4; r++)
                    out[(size_t)(mb + r) * EMB + n] = acc[mi][ni][r] + bv;
            } else {
                int b = mb >> 11, s0 = mb & 2047;
                int h = n >> 6,  d = n & 63;
                if (mode == 0) {
#pragma unroll
                    for (int r = 0; r < 4; r++) {
                        float val = acc[mi][ni][r] + bv;
                        size_t i128 = ((size_t)(b * NH + h) * SEQ + s0 + r) * 128 + d;
                        Qa[i128]      = f2b(val * (0.125f * LOG2E));
                        Qa[i128 + 64] = f2b(lamf * LOG2E * fast_tanh(val));
                    }
                } else if (mode == 1) {
#pragma unroll
                    for (int r = 0; r < 4; r++) {
                        float val = acc[mi][ni][r] + bv;
                        Ka[((size_t)(b * NH + h) * SEQ + s0 + r) * 128 + d] = f2b(val);
                    }
                } else {
                    u16x4 pk = pack4(acc[mi][ni][0] + bv, acc[mi][ni][1] + bv,
                                     acc[mi][ni][2] + bv, acc[mi][ni][3] + bv);
                    *(u16x4*)&Vt[((size_t)(b * NH + h) * HD + d) * SEQ + s0] = pk;
                }
            }
        }
}

// ---------------------------------------------------------------------------
// U kernel: Ka[:,64:128] = tanh(K) @ J_h^T per (b,h); K read from Ka[:,0:64]
// grid: (S/64, B*H), 256 threads
// ---------------------------------------------------------------------------
__global__ __launch_bounds__(256) void ukern(
        const float* __restrict__ J, u16* __restrict__ Ka)
{
    __shared__ __attribute__((aligned(16))) u16 sJ[64 * 72];
    const int t = threadIdx.x, w = t >> 6, L = t & 63, lr = L & 15, lq = L >> 4;
    const int rt = blockIdx.x, bh = blockIdx.y, h = bh & 15;

#pragma unroll
    for (int i = 0; i < 2; i++) {
        int c = t + 256 * i;
        int row = c >> 3, col = (c & 7) * 8;
        *(bf16x8*)&sJ[row * 72 + col] = cvt8(&J[(size_t)h * 4096 + row * 64 + col]);
    }
    __syncthreads();

    const u16* krow = &Ka[((size_t)bh * SEQ + rt * 64 + w * 16 + lr) * 128];
    bf16x8 a0 = tanh8(ldfrag(krow + lq * 8));
    bf16x8 a1 = tanh8(ldfrag(krow + lq * 8 + 32));
#pragma unroll
    for (int nt = 0; nt < 4; nt++) {
        f32x4 acc = {0.f, 0.f, 0.f, 0.f};
        acc = MFMA16(a0, ldfrag(&sJ[(nt * 16 + lr) * 72 + lq * 8]), acc);
        acc = MFMA16(a1, ldfrag(&sJ[(nt * 16 + lr) * 72 + lq * 8 + 32]), acc);
#pragma unroll
        for (int r = 0; r < 4; r++) {
            int j = rt * 64 + w * 16 + lq * 4 + r;
            Ka[((size_t)bh * SEQ + j) * 128 + 64 + nt * 16 + lr] = f2b(acc[r]);
        }
    }
}

// ---------------------------------------------------------------------------
// Causal flash, S^T formulation, BM=128, 256 blocks x 512 thr (8 waves),
// segments (qt=p, qt=15-p) per block = uniform 36 k-tiles.
// ROUND 3: T14 reg-staging. The global_load_lds dbuf did NOT overlap: the DMA
// writes sK[bsel] (runtime bsel) while compute ds_reads sK[cur]; the compiler
// cannot prove no-alias and drains vmcnt before the ds_reads -> stage was
// serialized with compute (~2000 stall cy/tile of the observed 3420). Now:
// per-lane global_load_dwordx4 -> regs issued at tile START (no LDS alias ->
// no wait before compute's ds_reads), compute, then vmcnt-gated ds_write_b128
// into buf^1 AFTER compute (latency fully hidden), one barrier per tile.
// Also: combine buffer sOt re-laid lane-major (stride-1 across lanes) -- the
// old stride-32-dword layout was a 32-way bank conflict (the +1.4M conflict
// cycles in round 2); and exp2 partial sums tree-reduced.
// ---------------------------------------------------------------------------
__global__ __launch_bounds__(512) void flash(
        const u16* __restrict__ Qa, const u16* __restrict__ Ka,
        const u16* __restrict__ Vt, u16* __restrict__ attn)
{
    __shared__ __attribute__((aligned(16))) u16 sK[2][64 * 128];   // 32 KB
    __shared__ __attribute__((aligned(16))) u16 sVt[2][64 * 64];   // 16 KB
    __shared__ __attribute__((aligned(16))) u16 sP[128 * 72];      // 18 KB
    __shared__ float sLs[2][4][64][2];                             // 4 KB

    const int t = threadIdx.x, w = t >> 6, L = t & 63, lr = L & 15, lq = L >> 4;
    const int wq = w & 3, wk = w >> 2;
    const int bh = blockIdx.x & 31, p = blockIdx.x >> 5;
    const int i_l = wq * 16 + lr;           // lane's q-row within a 64-set
    const u16* Kbase = Ka + (size_t)bh * SEQ * 128;
    const u16* Vbase = Vt + (size_t)bh * HD * SEQ;
    const int b = bh >> 4, h = bh & 15;
    float* sOt = reinterpret_cast<float*>(sK);   // 8192 floats (exactly 256*32)

    // per-lane staging addresses (pre-swizzled source, linear LDS dest):
    // K chunks c0 = t, c1 = 512+t (row = c>>4, col8 = (c&15)^(row&15));
    // V chunk  cv = t (d = t>>3, j8 = (t&7)^(d&7))
    const int kr0 = t >> 4,        kc0 = (t & 15) ^ (kr0 & 15);
    const int kr1 = (512 + t) >> 4, kc1 = (t & 15) ^ (kr1 & 15);
    const int vd = t >> 3,          vj8 = (t & 7) ^ (vd & 7);
    const u16* kq0 = Kbase + (size_t)kr0 * 128 + kc0 * 8;
    const u16* kq1 = Kbase + (size_t)kr1 * 128 + kc1 * 8;
    const u16* vq  = Vbase + (size_t)vd * SEQ + vj8 * 8;

#pragma unroll 1
    for (int seg = 0; seg < 2; seg++) {
        const int qt = seg ? 15 - p : p;
        const int qm = qt * 128;
        const int ktmax = 2 * qt + 1;

        // two Q B-operand sets: set g covers q-rows qm + g*64 + [0,64)
        bf16x8 qf[2][4];
#pragma unroll
        for (int g = 0; g < 2; g++) {
            const u16* qrow = Qa + ((size_t)bh * SEQ + qm + g * 64 + i_l) * 128;
#pragma unroll
            for (int s = 0; s < 4; s++) qf[g][s] = ldfrag(qrow + s * 32 + lq * 8);
        }

        f32x4 Ot[2][4];
#pragma unroll
        for (int g = 0; g < 2; g++)
#pragma unroll
            for (int i = 0; i < 4; i++) { f32x4 z = {0.f, 0.f, 0.f, 0.f}; Ot[g][i] = z; }
        float lsum[2] = {0.f, 0.f};

        // prologue: stage tile 0 into buffer 0 (load -> write, no overlap here)
        {
            int4 rk0 = *(const int4*)kq0;
            int4 rk1 = *(const int4*)kq1;
            int4 rv  = *(const int4*)vq;
            *(int4*)&sK[0][(size_t)t * 8]         = rk0;
            *(int4*)&sK[0][(size_t)(512 + t) * 8] = rk1;
            *(int4*)&sVt[0][(size_t)t * 8]        = rv;
        }
        __syncthreads();

        int cur = 0;
        for (int kt = 0; kt <= ktmax; kt++) {
            // issue next tile's global loads FIRST: latency hides under compute
            const bool pf = kt < ktmax;
            int4 rk0, rk1, rv;
            if (pf) {
                const int kn = (kt + 1) * 64;
                rk0 = *(const int4*)(kq0 + (size_t)kn * 128);
                rk1 = *(const int4*)(kq1 + (size_t)kn * 128);
                rv  = *(const int4*)(vq + kn);
            }
            const u16* sKc = sK[cur];
            const u16* sVc = sVt[cur];

            // S^T: group wk owns k-cols [wk*32, wk*32+32); each kf feeds 2 Q sets
            f32x4 sc[2][2];
#pragma unroll
            for (int g = 0; g < 2; g++)
#pragma unroll
                for (int m = 0; m < 2; m++) { f32x4 z = {0.f,0.f,0.f,0.f}; sc[g][m] = z; }
            __builtin_amdgcn_s_setprio(1);
#pragma unroll
            for (int mt2 = 0; mt2 < 2; mt2++) {
                int j = (wk * 2 + mt2) * 16 + lr;
#pragma unroll
                for (int s = 0; s < 4; s++) {
                    bf16x8 kf = ldfrag(&sKc[(j * 16 + ((s * 4 + lq) ^ (j & 15))) * 8]);
                    sc[0][mt2] = MFMA16(kf, qf[0][s], sc[0][mt2]);
                    sc[1][mt2] = MFMA16(kf, qf[1][s], sc[1][mt2]);
                }
            }
            __builtin_amdgcn_s_setprio(0);
            // causal masks only on the last two k-tiles
            if (kt >= ktmax - 1) {
                const int thr0 = (kt == ktmax) ? -1  : i_l;
                const int thr1 = (kt == ktmax) ? i_l : 63;
#pragma unroll
                for (int mt2 = 0; mt2 < 2; mt2++)
#pragma unroll
                    for (int r = 0; r < 4; r++) {
                        int j = (wk * 2 + mt2) * 16 + lq * 4 + r;
                        if (j > thr0) sc[0][mt2][r] = -INFINITY;
                        if (j > thr1) sc[1][mt2][r] = -INFINITY;
                    }
            }
            // no-max softmax: P = exp2(s); raw v_exp_f32 (exp2(-inf)=0 masked)
#pragma unroll
            for (int g = 0; g < 2; g++) {
#pragma unroll
                for (int mt2 = 0; mt2 < 2; mt2++) {
                    float e0 = __builtin_amdgcn_exp2f(sc[g][mt2][0]);
                    float e1 = __builtin_amdgcn_exp2f(sc[g][mt2][1]);
                    float e2 = __builtin_amdgcn_exp2f(sc[g][mt2][2]);
                    float e3 = __builtin_amdgcn_exp2f(sc[g][mt2][3]);
                    lsum[g] += (e0 + e1) + (e2 + e3);
                    *(u16x4*)&sP[(g * 64 + i_l) * 72 + (wk * 2 + mt2) * 16 + lq * 4] =
                        pack4(e0, e1, e2, e3);
                }
            }
            // O^T += V^T @ P^T over this group's k-fragment (s2 = wk)
            __builtin_amdgcn_s_setprio(1);
            {
                bf16x8 pf0 = ldfrag(&sP[(i_l) * 72 + wk * 32 + lq * 8]);
                bf16x8 pf1 = ldfrag(&sP[(64 + i_l) * 72 + wk * 32 + lq * 8]);
#pragma unroll
                for (int mt = 0; mt < 4; mt++) {
                    int d = mt * 16 + lr;
                    bf16x8 vf = ldfrag(&sVc[(d * 8 + ((wk * 4 + lq) ^ (d & 7))) * 8]);
                    Ot[0][mt] = MFMA16(vf, pf0, Ot[0][mt]);
                    Ot[1][mt] = MFMA16(vf, pf1, Ot[1][mt]);
                }
            }
            __builtin_amdgcn_s_setprio(0);
            // write prefetched tile into buf^1 (vmcnt wait lands here, hidden;
            // buf^1 was last read at tile t-1 behind the barrier -> safe)
            if (pf) {
                *(int4*)&sK[cur ^ 1][(size_t)t * 8]         = rk0;
                *(int4*)&sK[cur ^ 1][(size_t)(512 + t) * 8] = rk1;
                *(int4*)&sVt[cur ^ 1][(size_t)t * 8]        = rv;
            }
            __syncthreads();      // lgkmcnt(0): writes visible to all waves
            cur ^= 1;
        }

        // ---- combine k-split partials and write this segment's output ----
        // sOt lane-major: element e of lane (wq*64+L) at sOt[wq*64+L + 256*e]
        // -> every access is stride-1 across lanes = conflict-free
#pragma unroll
        for (int g = 0; g < 2; g++) {
            lsum[g] += __shfl_xor(lsum[g], 16);
            lsum[g] += __shfl_xor(lsum[g], 32);
            sLs[wk][wq][L][g] = lsum[g];
        }
        if (wk == 1) {
            float* dst = &sOt[wq * 64 + L];
#pragma unroll
            for (int g = 0; g < 2; g++)
#pragma unroll
                for (int mt = 0; mt < 4; mt++)
#pragma unroll
                    for (int r = 0; r < 4; r++)
                        dst[256 * (g * 16 + mt * 4 + r)] = Ot[g][mt][r];
        }
        __syncthreads();
        if (wk == 0) {
            const float* src = &sOt[wq * 64 + L];
#pragma unroll
            for (int g = 0; g < 2; g++) {
                float ls = lsum[g] + sLs[1][wq][L][g];
                const float r0 = __builtin_amdgcn_rcpf(ls);
                const float inv = r0 * (2.0f - ls * r0);  // NR refine
                const size_t base =
                    ((size_t)(b * SEQ + qm + g * 64 + i_l)) * EMB + h * HD;
#pragma unroll
                for (int mt = 0; mt < 4; mt++)
                    *(u16x4*)&attn[base + mt * 16 + lq * 4] = pack4(
                        (Ot[g][mt][0] + src[256 * (g * 16 + mt * 4 + 0)]) * inv,
                        (Ot[g][mt][1] + src[256 * (g * 16 + mt * 4 + 1)]) * inv,
                        (Ot[g][mt][2] + src[256 * (g * 16 + mt * 4 + 2)]) * inv,
                        (Ot[g][mt][3] + src[256 * (g * 16 + mt * 4 + 3)]) * inv);
            }
        }
        __syncthreads();   // protect sOt/sLs before next segment's staging
    }
}

// ---------------------------------------------------------------------------
extern "C" void kernel_launch(void* const* d_in, const int* in_sizes, int n_in,
                              void* d_out, int out_size, void* d_ws, size_t ws_size,
                              hipStream_t stream)
{
    const float* x   = (const float*)d_in[0];
    const float* Wq  = (const float*)d_in[1];
    const float* bq  = (const float*)d_in[2];
    const float* Wk  = (const float*)d_in[3];
    const float* bk  = (const float*)d_in[4];
    const float* Wv  = (const float*)d_in[5];
    const float* bv  = (const float*)d_in[6];
    const float* Wo  = (const float*)d_in[7];
    const float* bo  = (const float*)d_in[8];
    const float* J   = (const float*)d_in[9];
    const float* lam = (const float*)d_in[10];

    u16* ws  = (u16*)d_ws;
    u16* xb  = ws;                                   // 4096*1024 bf16 (reused as attn)
    u16* Wqb = xb  + (size_t)4096 * 1024;
    u16* Wkb = Wqb + (size_t)1024 * 1024;
    u16* Wvb = Wkb + (size_t)1024 * 1024;
    u16* Wob = Wvb + (size_t)1024 * 1024;
    u16* Qa  = Wob + (size_t)1024 * 1024;            // 32*2048*128
    u16* Ka  = Qa  + (size_t)32 * 2048 * 128;        // 32*2048*128
    u16* Vt  = Ka  + (size_t)32 * 2048 * 128;        // 32*64*2048 (b,h,d,s)
    u16* attn = xb;                                  // alias: xb dead after QKV
    float* dout = (float*)d_out;

    dim3 blk(256);
    // fp32 -> bf16 for x and the four weight matrices
    cvt_all<<<dim3(4096), blk, 0, stream>>>(x, Wq, Wk, Wv, Wo, ws);
    // fused Q/K/V projections (BK=64)
    gemm_epi<4><<<dim3(8, 32, 3), blk, 0, stream>>>(
        xb, Wqb, bq, Wkb, bk, Wvb, bv, lam, Qa, Ka, Vt, dout, 0);
    // Ka[:,64:128] = tanh(K) @ J_h^T
    ukern<<<dim3(32, 32), blk, 0, stream>>>(J, Ka);
    // causal flash attention: 256 blocks x 512 thr, qt pair (p, 15-p) per block
    flash<<<dim3(256), dim3(512), 0, stream>>>(Qa, Ka, Vt, attn);
    // output projection (64-row tiles -> 512 blocks for occupancy)
    gemm_epi<2><<<dim3(8, 64, 1), blk, 0, stream>>>(
        attn, Wob, bo, Wob, bo, Wob, bo, lam, Qa, Ka, Vt, dout, 3);
}

// Round 4
// 186.079 us; speedup vs baseline: 1.1466x; 1.0252x over previous
//
#include <hip/hip_runtime.h>
#include <hip/hip_bf16.h>

typedef unsigned short u16;
typedef __bf16 bf16x8 __attribute__((ext_vector_type(8)));
typedef float f32x4 __attribute__((ext_vector_type(4)));
typedef unsigned short u16x4 __attribute__((ext_vector_type(4)));

#define MFMA16(a, b, c) __builtin_amdgcn_mfma_f32_16x16x32_bf16(a, b, c, 0, 0, 0)

#define EMB 1024
#define SEQ 2048
#define NH 16
#define HD 64
#define LOG2E 1.4426950408889634f

// async global->LDS, 16B per lane; LDS dest = wave-uniform base + lane*16
#define GLOAD_LDS16(g, l) __builtin_amdgcn_global_load_lds( \
    (const __attribute__((address_space(1))) unsigned int*)(g), \
    (__attribute__((address_space(3))) unsigned int*)(l), 16, 0, 0)

__device__ __forceinline__ float b2f(u16 u) {
    union { unsigned int i; float f; } v; v.i = ((unsigned int)u) << 16; return v.f;
}
__device__ __forceinline__ u16 f2b(float f) {
    __hip_bfloat16 h = __float2bfloat16(f);
    return *reinterpret_cast<u16*>(&h);
}
__device__ __forceinline__ u16x4 pack4(float a, float b, float c, float d) {
    union { __hip_bfloat162 h2[2]; u16x4 u; } r;
    r.h2[0] = __float22bfloat162_rn(float2{a, b});
    r.h2[1] = __float22bfloat162_rn(float2{c, d});
    return r.u;
}
__device__ __forceinline__ bf16x8 ldfrag(const u16* p) {
    return *reinterpret_cast<const bf16x8*>(p);
}
__device__ __forceinline__ bf16x8 cvt8(const float* p) {
    const float4 a = *reinterpret_cast<const float4*>(p);
    const float4 b = *reinterpret_cast<const float4*>(p + 4);
    union { u16x4 q[2]; bf16x8 v; } r;
    r.q[0] = pack4(a.x, a.y, a.z, a.w);
    r.q[1] = pack4(b.x, b.y, b.z, b.w);
    return r.v;
}
// tanh via hw exp2 + rcp: rel err < 1e-6, safe for |x| < 40
__device__ __forceinline__ float fast_tanh(float x) {
    float t = __builtin_amdgcn_exp2f(x * (2.0f * LOG2E));
    return 1.0f - 2.0f * __builtin_amdgcn_rcpf(t + 1.0f);
}

// ---------------------------------------------------------------------------
// fp32 -> bf16: [x (4096x1024) | Wq | Wk | Wv | Wo] -> ws bf16, and
// J (16x64x64) -> Jb at ws + 29360128 (u16 elems)
// ---------------------------------------------------------------------------
__global__ __launch_bounds__(256) void cvt_all(
        const float* __restrict__ x,  const float* __restrict__ Wq,
        const float* __restrict__ Wk, const float* __restrict__ Wv,
        const float* __restrict__ Wo, const float* __restrict__ J,
        u16* __restrict__ dst)
{
    size_t i = ((size_t)blockIdx.x * 256 + threadIdx.x) * 8;
    const float* src; size_t off; u16* d;
    if (i < 4194304) { src = x; off = i; d = dst + i; }
    else if (i < 8388608) {
        size_t j = i - 4194304; int w = (int)(j >> 20); off = j & 1048575;
        src = (w == 0) ? Wq : (w == 1) ? Wk : (w == 2) ? Wv : Wo;
        d = dst + i;
    } else {
        off = i - 8388608; src = J; d = dst + 29360128 + off;
    }
    *(bf16x8*)d = cvt8(src + off);
}

// ---------------------------------------------------------------------------
// GEMM: C = A(MxK,bf16) @ W(NxK,bf16)^T + bias(fp32). Tile MI*32 x 128, BK=64.
// mode 0: Qa[:,0:64]=Q/8*log2e, Qa[:,64:128]=lam*log2e*tanh(Q)
// mode 1: Ka[:,0:64]=K  AND (fused, was ukern) Ka[:,64:128]=tanh(K)@J_h^T:
//         wave (wm,wn) holds rows wm*64+[0,64) x head (n0>>6)+wn complete ->
//         stage tanh(K) into dead sA/sB (XOR-swizzled [64][64] per wave),
//         J-frags straight from global bf16 Jb (L2-hot), ukern's MFMA pattern.
// mode 2: Vt[b,h,d,s]=V (transposed)
// mode 3: out = val fp32
// ---------------------------------------------------------------------------
template<int MI>   // m-frags per wave (4 -> 128-row tile, 2 -> 64-row tile)
__global__ __launch_bounds__(256, 4) void gemm_epi(
        const u16* __restrict__ A,
        const u16* __restrict__ W0, const float* __restrict__ B0,
        const u16* __restrict__ W1, const float* __restrict__ B1,
        const u16* __restrict__ W2, const float* __restrict__ B2,
        const float* __restrict__ lam, const u16* __restrict__ Jb,
        u16* __restrict__ Qa, u16* __restrict__ Ka, u16* __restrict__ Vt,
        float* __restrict__ out, int modeBase)
{
    const int mode = modeBase + blockIdx.z;
    const u16* W; const float* bias;
    if (blockIdx.z == 0)      { W = W0; bias = B0; }
    else if (blockIdx.z == 1) { W = W1; bias = B1; }
    else                      { W = W2; bias = B2; }

    __shared__ __attribute__((aligned(16))) u16 sA[MI * 32 * 64];
    __shared__ __attribute__((aligned(16))) u16 sB[128 * 64];

    const int t = threadIdx.x;
    const int w = t >> 6, L = t & 63;
    const int wm = w >> 1, wn = w & 1;
    const int lr = L & 15, lq = L >> 4;
    const int wbase = t & 192;                   // wave*64
    const int m0 = blockIdx.y * (MI * 32), n0 = blockIdx.x * 128;

    f32x4 acc[MI][4];
#pragma unroll
    for (int i = 0; i < MI; i++)
#pragma unroll
        for (int j = 0; j < 4; j++) { f32x4 z = {0.f, 0.f, 0.f, 0.f}; acc[i][j] = z; }

    for (int k0 = 0; k0 < EMB; k0 += 64) {
        __syncthreads();
        // stage A: MI*256 chunks of 8 elems (8 chunks/row), col8 = cc ^ (row&7)
#pragma unroll
        for (int q = 0; q < MI; q++) {
            int c = q * 256 + t;
            int row = c >> 3, cc = c & 7;
            int col8 = cc ^ (row & 7);
            GLOAD_LDS16(&A[(size_t)(m0 + row) * EMB + k0 + col8 * 8],
                        &sA[(q * 256 + wbase) * 8]);
        }
        // stage B: 1024 chunks
#pragma unroll
        for (int q = 0; q < 4; q++) {
            int c = q * 256 + t;
            int row = c >> 3, cc = c & 7;
            int col8 = cc ^ (row & 7);
            GLOAD_LDS16(&W[(size_t)(n0 + row) * EMB + k0 + col8 * 8],
                        &sB[(q * 256 + wbase) * 8]);
        }
        __syncthreads();
        // two 32-k sub-chunks; fragments loaded per sub-chunk to bound VGPR
#pragma unroll
        for (int s = 0; s < 2; s++) {
            bf16x8 af[MI], bfr[4];
#pragma unroll
            for (int mi = 0; mi < MI; mi++) {
                int row = wm * (MI * 16) + mi * 16 + lr;
                af[mi] = ldfrag(&sA[(row * 8 + ((s * 4 + lq) ^ (row & 7))) * 8]);
            }
#pragma unroll
            for (int ni = 0; ni < 4; ni++) {
                int row = wn * 64 + ni * 16 + lr;
                bfr[ni] = ldfrag(&sB[(row * 8 + ((s * 4 + lq) ^ (row & 7))) * 8]);
            }
#pragma unroll
            for (int mi = 0; mi < MI; mi++)
#pragma unroll
                for (int ni = 0; ni < 4; ni++)
                    acc[mi][ni] = MFMA16(af[mi], bfr[ni], acc[mi][ni]);
        }
    }

    // mode 1 reuses sA/sB for tanh(K); main-loop frag reads must be done
    if (mode == 1) __syncthreads();
    u16* sU = (w < 2) ? &sA[(size_t)w * 4096] : &sB[(size_t)(w - 2) * 4096];

    const float lamf = lam[0];
#pragma unroll
    for (int mi = 0; mi < MI; mi++)
#pragma unroll
        for (int ni = 0; ni < 4; ni++) {
            int mb = m0 + wm * (MI * 16) + mi * 16 + lq * 4;
            int n  = n0 + wn * 64 + ni * 16 + lr;
            float bv = bias[n];
            if (mode == 3) {
#pragma unroll
                for (int r = 0; r < 4; r++)
                    out[(size_t)(mb + r) * EMB + n] = acc[mi][ni][r] + bv;
            } else {
                int b = mb >> 11, s0 = mb & 2047;
                int h = n >> 6,  d = n & 63;
                if (mode == 0) {
#pragma unroll
                    for (int r = 0; r < 4; r++) {
                        float val = acc[mi][ni][r] + bv;
                        size_t i128 = ((size_t)(b * NH + h) * SEQ + s0 + r) * 128 + d;
                        Qa[i128]      = f2b(val * (0.125f * LOG2E));
                        Qa[i128 + 64] = f2b(lamf * LOG2E * fast_tanh(val));
                    }
                } else if (mode == 1) {
#pragma unroll
                    for (int r = 0; r < 4; r++) {
                        float val = acc[mi][ni][r] + bv;
                        Ka[((size_t)(b * NH + h) * SEQ + s0 + r) * 128 + d] = f2b(val);
                        // stage tanh(K) into per-wave LDS [64][64], XOR-swizzled
                        int row64 = mi * 16 + lq * 4 + r;     // local row
                        int phys = (d >> 3) ^ (row64 & 7);
                        sU[row64 * 64 + phys * 8 + (d & 7)] = f2b(fast_tanh(val));
                    }
                } else {
                    u16x4 pk = pack4(acc[mi][ni][0] + bv, acc[mi][ni][1] + bv,
                                     acc[mi][ni][2] + bv, acc[mi][ni][3] + bv);
                    *(u16x4*)&Vt[((size_t)(b * NH + h) * HD + d) * SEQ + s0] = pk;
                }
            }
        }

    // fused U kernel: Ka[:,64:128] = tanh(K) @ J_h^T (ukern's exact pattern)
    if (mode == 1) {
        const int hn = (n0 >> 6) + wn;
        const u16* Jh = Jb + (size_t)hn * 4096;
        bf16x8 jf[4][2];
#pragma unroll
        for (int nt = 0; nt < 4; nt++)
#pragma unroll
            for (int s2 = 0; s2 < 2; s2++)
                jf[nt][s2] = ldfrag(&Jh[(nt * 16 + lr) * 64 + s2 * 32 + lq * 8]);
#pragma unroll
        for (int rt2 = 0; rt2 < 4; rt2++) {
            int r64 = rt2 * 16 + lr;
            bf16x8 a0 = ldfrag(&sU[r64 * 64 + ((0 + lq) ^ (r64 & 7)) * 8]);
            bf16x8 a1 = ldfrag(&sU[r64 * 64 + ((4 + lq) ^ (r64 & 7)) * 8]);
#pragma unroll
            for (int nt = 0; nt < 4; nt++) {
                f32x4 acc2 = {0.f, 0.f, 0.f, 0.f};
                acc2 = MFMA16(a0, jf[nt][0], acc2);
                acc2 = MFMA16(a1, jf[nt][1], acc2);
#pragma unroll
                for (int r = 0; r < 4; r++) {
                    int grow = m0 + wm * 64 + rt2 * 16 + lq * 4 + r;
                    int bb = grow >> 11, ss = grow & 2047;
                    Ka[((size_t)(bb * NH + hn) * SEQ + ss) * 128 + 64 + nt * 16 + lr]
                        = f2b(acc2[r]);
                }
            }
        }
    }
}

// ---------------------------------------------------------------------------
// Causal flash, S^T formulation, BM=128, 256 blocks x 512 thr (8 waves),
// segments (qt=p, qt=15-p) per block = uniform 17 k-tiles.
// ROUND 4: KVBLK 64 -> 128. Pipe arithmetic at the measured MFMA rate
// (16x16x32 ~19.4 cy/SIMD) showed per-64-tile: ~930 cy MFMA + ~650 VALU of a
// measured 3250 -> ~50% is per-tile FIXED cost (8-wave barrier lockstep,
// stage vmcnt exposure, loop overhead). Doubling the k-tile halves tile count
// 34 -> 17 at identical MFMA/VALU totals (diagonal-mask waste unchanged at
// 50% of one tile). LDS 71 -> 134 KB, still 1 block/CU (= current residency).
// Keeps: reg-staged dbuf (loads at tile start, ds_writes after compute),
// one barrier/tile, setprio, raw exp2, lane-major combine buffer.
// 8 waves split the 128-k tile: group wk owns k [wk*64, wk*64+64).
// ---------------------------------------------------------------------------
__global__ __launch_bounds__(512) void flash(
        const u16* __restrict__ Qa, const u16* __restrict__ Ka,
        const u16* __restrict__ Vt, u16* __restrict__ attn)
{
    __shared__ __attribute__((aligned(16))) u16 sK[2][128 * 128];  // 64 KB
    __shared__ __attribute__((aligned(16))) u16 sVt[2][64 * 128];  // 32 KB
    __shared__ __attribute__((aligned(16))) u16 sP[128 * 136];     // 34 KB
    __shared__ float sLs[2][4][64][2];                             // 4 KB

    const int t = threadIdx.x, w = t >> 6, L = t & 63, lr = L & 15, lq = L >> 4;
    const int wq = w & 3, wk = w >> 2;
    const int bh = blockIdx.x & 31, p = blockIdx.x >> 5;
    const int i_l = wq * 16 + lr;           // lane's q-row within a 64-set
    const u16* Kbase = Ka + (size_t)bh * SEQ * 128;
    const u16* Vbase = Vt + (size_t)bh * HD * SEQ;
    const int b = bh >> 4, h = bh & 15;
    float* sOt = reinterpret_cast<float*>(sK);   // 32 KB combine buffer (fits)

    // per-lane staging addresses (pre-swizzled source, linear LDS dest):
    // K tile 128x128: 2048 chunks (16/row), col8 = cc ^ (row&15), 4 per lane
    // V^T tile 64x128: 1024 chunks (16/row), j8 = cc ^ (d&7),     2 per lane
    const u16* kq[4];
#pragma unroll
    for (int q = 0; q < 4; q++) {
        int c = q * 512 + t;
        int row = c >> 4, cc = c & 15;
        kq[q] = Kbase + (size_t)row * 128 + (cc ^ (row & 15)) * 8;
    }
    const u16* vq[2];
#pragma unroll
    for (int q = 0; q < 2; q++) {
        int c = q * 512 + t;
        int d = c >> 4, cc = c & 15;
        vq[q] = Vbase + (size_t)d * SEQ + (cc ^ (d & 7)) * 8;
    }

#pragma unroll 1
    for (int seg = 0; seg < 2; seg++) {
        const int qt = seg ? 15 - p : p;
        const int qm = qt * 128;

        // two Q B-operand sets: set g covers q-rows qm + g*64 + [0,64)
        bf16x8 qf[2][4];
#pragma unroll
        for (int g = 0; g < 2; g++) {
            const u16* qrow = Qa + ((size_t)bh * SEQ + qm + g * 64 + i_l) * 128;
#pragma unroll
            for (int s = 0; s < 4; s++) qf[g][s] = ldfrag(qrow + s * 32 + lq * 8);
        }

        f32x4 Ot[2][4];
#pragma unroll
        for (int g = 0; g < 2; g++)
#pragma unroll
            for (int i = 0; i < 4; i++) { f32x4 z = {0.f, 0.f, 0.f, 0.f}; Ot[g][i] = z; }
        float lsum[2] = {0.f, 0.f};

        // prologue: stage tile 0 into buffer 0
        {
            int4 a0 = *(const int4*)kq[0];
            int4 a1 = *(const int4*)kq[1];
            int4 a2 = *(const int4*)kq[2];
            int4 a3 = *(const int4*)kq[3];
            int4 b0 = *(const int4*)vq[0];
            int4 b1 = *(const int4*)vq[1];
            *(int4*)&sK[0][(size_t)(0 * 512 + t) * 8] = a0;
            *(int4*)&sK[0][(size_t)(1 * 512 + t) * 8] = a1;
            *(int4*)&sK[0][(size_t)(2 * 512 + t) * 8] = a2;
            *(int4*)&sK[0][(size_t)(3 * 512 + t) * 8] = a3;
            *(int4*)&sVt[0][(size_t)(0 * 512 + t) * 8] = b0;
            *(int4*)&sVt[0][(size_t)(1 * 512 + t) * 8] = b1;
        }
        __syncthreads();

        int cur = 0;
        for (int kt = 0; kt <= qt; kt++) {
            // issue next tile's global loads FIRST: latency hides under compute
            const bool pf = kt < qt;
            int4 rk0, rk1, rk2, rk3, rv0, rv1;
            if (pf) {
                const int kn = (kt + 1) * 128;
                rk0 = *(const int4*)(kq[0] + (size_t)kn * 128);
                rk1 = *(const int4*)(kq[1] + (size_t)kn * 128);
                rk2 = *(const int4*)(kq[2] + (size_t)kn * 128);
                rk3 = *(const int4*)(kq[3] + (size_t)kn * 128);
                rv0 = *(const int4*)(vq[0] + kn);
                rv1 = *(const int4*)(vq[1] + kn);
            }
            const u16* sKc = sK[cur];
            const u16* sVc = sVt[cur];

            // S^T: group wk owns k-rows [wk*64, wk*64+64); each kf feeds 2 Q sets
            f32x4 sc[2][4];
#pragma unroll
            for (int g = 0; g < 2; g++)
#pragma unroll
                for (int m = 0; m < 4; m++) { f32x4 z = {0.f,0.f,0.f,0.f}; sc[g][m] = z; }
            __builtin_amdgcn_s_setprio(1);
#pragma unroll
            for (int mt2 = 0; mt2 < 4; mt2++) {
                int j = wk * 64 + mt2 * 16 + lr;
#pragma unroll
                for (int s = 0; s < 4; s++) {
                    bf16x8 kf = ldfrag(&sKc[(j * 16 + ((s * 4 + lq) ^ (j & 15))) * 8]);
                    sc[0][mt2] = MFMA16(kf, qf[0][s], sc[0][mt2]);
                    sc[1][mt2] = MFMA16(kf, qf[1][s], sc[1][mt2]);
                }
            }
            __builtin_amdgcn_s_setprio(0);
            // causal mask: only the diagonal tile (kt == qt)
            if (kt == qt) {
#pragma unroll
                for (int mt2 = 0; mt2 < 4; mt2++)
#pragma unroll
                    for (int r = 0; r < 4; r++) {
                        int jj = wk * 64 + mt2 * 16 + lq * 4 + r;
                        if (jj > i_l)      sc[0][mt2][r] = -INFINITY;
                        if (jj > 64 + i_l) sc[1][mt2][r] = -INFINITY;
                    }
            }
            // no-max softmax: P = exp2(s); raw v_exp_f32 (exp2(-inf)=0 masked)
#pragma unroll
            for (int g = 0; g < 2; g++) {
#pragma unroll
                for (int mt2 = 0; mt2 < 4; mt2++) {
                    float e0 = __builtin_amdgcn_exp2f(sc[g][mt2][0]);
                    float e1 = __builtin_amdgcn_exp2f(sc[g][mt2][1]);
                    float e2 = __builtin_amdgcn_exp2f(sc[g][mt2][2]);
                    float e3 = __builtin_amdgcn_exp2f(sc[g][mt2][3]);
                    lsum[g] += (e0 + e1) + (e2 + e3);
                    *(u16x4*)&sP[(g * 64 + i_l) * 136 + wk * 64 + mt2 * 16 + lq * 4] =
                        pack4(e0, e1, e2, e3);
                }
            }
            // O^T += V^T @ P^T over this group's 64-k slice (2 k-frags)
            __builtin_amdgcn_s_setprio(1);
#pragma unroll
            for (int s2l = 0; s2l < 2; s2l++) {
                bf16x8 pf0 = ldfrag(&sP[(i_l) * 136 + wk * 64 + s2l * 32 + lq * 8]);
                bf16x8 pf1 = ldfrag(&sP[(64 + i_l) * 136 + wk * 64 + s2l * 32 + lq * 8]);
#pragma unroll
                for (int mt = 0; mt < 4; mt++) {
                    int d = mt * 16 + lr;
                    bf16x8 vf = ldfrag(
                        &sVc[(d * 16 + ((wk * 8 + s2l * 4 + lq) ^ (d & 7))) * 8]);
                    Ot[0][mt] = MFMA16(vf, pf0, Ot[0][mt]);
                    Ot[1][mt] = MFMA16(vf, pf1, Ot[1][mt]);
                }
            }
            __builtin_amdgcn_s_setprio(0);
            // write prefetched tile into buf^1 (vmcnt wait lands here, hidden)
            if (pf) {
                *(int4*)&sK[cur ^ 1][(size_t)(0 * 512 + t) * 8] = rk0;
                *(int4*)&sK[cur ^ 1][(size_t)(1 * 512 + t) * 8] = rk1;
                *(int4*)&sK[cur ^ 1][(size_t)(2 * 512 + t) * 8] = rk2;
                *(int4*)&sK[cur ^ 1][(size_t)(3 * 512 + t) * 8] = rk3;
                *(int4*)&sVt[cur ^ 1][(size_t)(0 * 512 + t) * 8] = rv0;
                *(int4*)&sVt[cur ^ 1][(size_t)(1 * 512 + t) * 8] = rv1;
            }
            __syncthreads();
            cur ^= 1;
        }

        // ---- combine k-split partials and write this segment's output ----
        // sOt lane-major: element e of lane (wq*64+L) at sOt[wq*64+L + 256*e]
#pragma unroll
        for (int g = 0; g < 2; g++) {
            lsum[g] += __shfl_xor(lsum[g], 16);
            lsum[g] += __shfl_xor(lsum[g], 32);
            sLs[wk][wq][L][g] = lsum[g];
        }
        if (wk == 1) {
            float* dst = &sOt[wq * 64 + L];
#pragma unroll
            for (int g = 0; g < 2; g++)
#pragma unroll
                for (int mt = 0; mt < 4; mt++)
#pragma unroll
                    for (int r = 0; r < 4; r++)
                        dst[256 * (g * 16 + mt * 4 + r)] = Ot[g][mt][r];
        }
        __syncthreads();
        if (wk == 0) {
            const float* src = &sOt[wq * 64 + L];
#pragma unroll
            for (int g = 0; g < 2; g++) {
                float ls = lsum[g] + sLs[1][wq][L][g];
                const float r0 = __builtin_amdgcn_rcpf(ls);
                const float inv = r0 * (2.0f - ls * r0);  // NR refine
                const size_t base =
                    ((size_t)(b * SEQ + qm + g * 64 + i_l)) * EMB + h * HD;
#pragma unroll
                for (int mt = 0; mt < 4; mt++)
                    *(u16x4*)&attn[base + mt * 16 + lq * 4] = pack4(
                        (Ot[g][mt][0] + src[256 * (g * 16 + mt * 4 + 0)]) * inv,
                        (Ot[g][mt][1] + src[256 * (g * 16 + mt * 4 + 1)]) * inv,
                        (Ot[g][mt][2] + src[256 * (g * 16 + mt * 4 + 2)]) * inv,
                        (Ot[g][mt][3] + src[256 * (g * 16 + mt * 4 + 3)]) * inv);
            }
        }
        __syncthreads();   // protect sOt/sLs before next segment's staging
    }
}

// ---------------------------------------------------------------------------
extern "C" void kernel_launch(void* const* d_in, const int* in_sizes, int n_in,
                              void* d_out, int out_size, void* d_ws, size_t ws_size,
                              hipStream_t stream)
{
    const float* x   = (const float*)d_in[0];
    const float* Wq  = (const float*)d_in[1];
    const float* bq  = (const float*)d_in[2];
    const float* Wk  = (const float*)d_in[3];
    const float* bk  = (const float*)d_in[4];
    const float* Wv  = (const float*)d_in[5];
    const float* bv  = (const float*)d_in[6];
    const float* Wo  = (const float*)d_in[7];
    const float* bo  = (const float*)d_in[8];
    const float* J   = (const float*)d_in[9];
    const float* lam = (const float*)d_in[10];

    u16* ws  = (u16*)d_ws;
    u16* xb  = ws;                                   // 4096*1024 bf16 (reused as attn)
    u16* Wqb = xb  + (size_t)4096 * 1024;
    u16* Wkb = Wqb + (size_t)1024 * 1024;
    u16* Wvb = Wkb + (size_t)1024 * 1024;
    u16* Wob = Wvb + (size_t)1024 * 1024;
    u16* Qa  = Wob + (size_t)1024 * 1024;            // 32*2048*128
    u16* Ka  = Qa  + (size_t)32 * 2048 * 128;        // 32*2048*128
    u16* Vt  = Ka  + (size_t)32 * 2048 * 128;        // 32*64*2048 (b,h,d,s)
    u16* Jb  = Vt  + (size_t)32 * 64 * 2048;         // 16*64*64 bf16 (= ws+29360128)
    u16* attn = xb;                                  // alias: xb dead after QKV
    float* dout = (float*)d_out;

    dim3 blk(256);
    // fp32 -> bf16 for x, the four weight matrices, and J
    cvt_all<<<dim3(4128), blk, 0, stream>>>(x, Wq, Wk, Wv, Wo, J, ws);
    // fused Q/K/V projections (BK=64); mode 1 also produces Ka[:,64:128]
    gemm_epi<4><<<dim3(8, 32, 3), blk, 0, stream>>>(
        xb, Wqb, bq, Wkb, bk, Wvb, bv, lam, Jb, Qa, Ka, Vt, dout, 0);
    // causal flash attention: 256 blocks x 512 thr, qt pair (p, 15-p) per block
    flash<<<dim3(256), dim3(512), 0, stream>>>(Qa, Ka, Vt, attn);
    // output projection (64-row tiles -> 512 blocks for occupancy)
    gemm_epi<2><<<dim3(8, 64, 1), blk, 0, stream>>>(
        attn, Wob, bo, Wob, bo, Wob, bo, lam, Jb, Qa, Ka, Vt, dout, 3);
}

// Round 5
// 184.097 us; speedup vs baseline: 1.1590x; 1.0108x over previous
//
#include <hip/hip_runtime.h>
#include <hip/hip_bf16.h>

typedef unsigned short u16;
typedef __bf16 bf16x8 __attribute__((ext_vector_type(8)));
typedef float f32x4 __attribute__((ext_vector_type(4)));
typedef unsigned short u16x4 __attribute__((ext_vector_type(4)));

#define MFMA16(a, b, c) __builtin_amdgcn_mfma_f32_16x16x32_bf16(a, b, c, 0, 0, 0)

#define EMB 1024
#define SEQ 2048
#define NH 16
#define HD 64
#define LOG2E 1.4426950408889634f

// async global->LDS, 16B per lane; LDS dest = wave-uniform base + lane*16
#define GLOAD_LDS16(g, l) __builtin_amdgcn_global_load_lds( \
    (const __attribute__((address_space(1))) unsigned int*)(g), \
    (__attribute__((address_space(3))) unsigned int*)(l), 16, 0, 0)

__device__ __forceinline__ float b2f(u16 u) {
    union { unsigned int i; float f; } v; v.i = ((unsigned int)u) << 16; return v.f;
}
__device__ __forceinline__ u16 f2b(float f) {
    __hip_bfloat16 h = __float2bfloat16(f);
    return *reinterpret_cast<u16*>(&h);
}
__device__ __forceinline__ u16x4 pack4(float a, float b, float c, float d) {
    union { __hip_bfloat162 h2[2]; u16x4 u; } r;
    r.h2[0] = __float22bfloat162_rn(float2{a, b});
    r.h2[1] = __float22bfloat162_rn(float2{c, d});
    return r.u;
}
__device__ __forceinline__ bf16x8 ldfrag(const u16* p) {
    return *reinterpret_cast<const bf16x8*>(p);
}
__device__ __forceinline__ bf16x8 cvt8(const float* p) {
    const float4 a = *reinterpret_cast<const float4*>(p);
    const float4 b = *reinterpret_cast<const float4*>(p + 4);
    union { u16x4 q[2]; bf16x8 v; } r;
    r.q[0] = pack4(a.x, a.y, a.z, a.w);
    r.q[1] = pack4(b.x, b.y, b.z, b.w);
    return r.v;
}
// tanh via hw exp2 + rcp: rel err < 1e-6, safe for |x| < 40
__device__ __forceinline__ float fast_tanh(float x) {
    float t = __builtin_amdgcn_exp2f(x * (2.0f * LOG2E));
    return 1.0f - 2.0f * __builtin_amdgcn_rcpf(t + 1.0f);
}

// ---------------------------------------------------------------------------
// fp32 -> bf16: [x (4096x1024) | Wq | Wk | Wv | Wo] -> ws bf16, and
// J (16x64x64) -> Jb at ws + 29360128 (u16 elems)
// ---------------------------------------------------------------------------
__global__ __launch_bounds__(256) void cvt_all(
        const float* __restrict__ x,  const float* __restrict__ Wq,
        const float* __restrict__ Wk, const float* __restrict__ Wv,
        const float* __restrict__ Wo, const float* __restrict__ J,
        u16* __restrict__ dst)
{
    size_t i = ((size_t)blockIdx.x * 256 + threadIdx.x) * 8;
    const float* src; size_t off; u16* d;
    if (i < 4194304) { src = x; off = i; d = dst + i; }
    else if (i < 8388608) {
        size_t j = i - 4194304; int w = (int)(j >> 20); off = j & 1048575;
        src = (w == 0) ? Wq : (w == 1) ? Wk : (w == 2) ? Wv : Wo;
        d = dst + i;
    } else {
        off = i - 8388608; src = J; d = dst + 29360128 + off;
    }
    *(bf16x8*)d = cvt8(src + off);
}

// ---------------------------------------------------------------------------
// GEMM: C = A(MxK,bf16) @ W(NxK,bf16)^T + bias(fp32). Tile MI*32 x 128, BK=64.
// ROUND 5: C^T accumulator orientation — MFMA operands swapped
// (A-op = W-frag, B-op = x-frag), so C row (lq*4+r) = n/d axis and C col
// (lr) = s axis. Every epilogue write along d vectorizes to u16x4/float4:
//   mode 0: 2 u16x4 per tile (was 8 scalar u16 + 2-byte HBM granularity)
//   mode 1: u16x4 K-store + u16x4 LDS staging; fused-U output u16x4
//   mode 3: float4 (was 4 scalar floats)
//   mode 2: 4 scalar u16 (d is register axis, Vt is d-major) — acceptable
// Main loop / staging / swizzles unchanged.
// ---------------------------------------------------------------------------
template<int MI>   // m-frags per wave (4 -> 128-row tile, 2 -> 64-row tile)
__global__ __launch_bounds__(256, 4) void gemm_epi(
        const u16* __restrict__ A,
        const u16* __restrict__ W0, const float* __restrict__ B0,
        const u16* __restrict__ W1, const float* __restrict__ B1,
        const u16* __restrict__ W2, const float* __restrict__ B2,
        const float* __restrict__ lam, const u16* __restrict__ Jb,
        u16* __restrict__ Qa, u16* __restrict__ Ka, u16* __restrict__ Vt,
        float* __restrict__ out, int modeBase)
{
    const int mode = modeBase + blockIdx.z;
    const u16* W; const float* bias;
    if (blockIdx.z == 0)      { W = W0; bias = B0; }
    else if (blockIdx.z == 1) { W = W1; bias = B1; }
    else                      { W = W2; bias = B2; }

    __shared__ __attribute__((aligned(16))) u16 sA[MI * 32 * 64];
    __shared__ __attribute__((aligned(16))) u16 sB[128 * 64];

    const int t = threadIdx.x;
    const int w = t >> 6, L = t & 63;
    const int wm = w >> 1, wn = w & 1;
    const int lr = L & 15, lq = L >> 4;
    const int wbase = t & 192;                   // wave*64
    const int m0 = blockIdx.y * (MI * 32), n0 = blockIdx.x * 128;

    f32x4 acc[MI][4];
#pragma unroll
    for (int i = 0; i < MI; i++)
#pragma unroll
        for (int j = 0; j < 4; j++) { f32x4 z = {0.f, 0.f, 0.f, 0.f}; acc[i][j] = z; }

    for (int k0 = 0; k0 < EMB; k0 += 64) {
        __syncthreads();
        // stage A: MI*256 chunks of 8 elems (8 chunks/row), col8 = cc ^ (row&7)
#pragma unroll
        for (int q = 0; q < MI; q++) {
            int c = q * 256 + t;
            int row = c >> 3, cc = c & 7;
            int col8 = cc ^ (row & 7);
            GLOAD_LDS16(&A[(size_t)(m0 + row) * EMB + k0 + col8 * 8],
                        &sA[(q * 256 + wbase) * 8]);
        }
        // stage B: 1024 chunks
#pragma unroll
        for (int q = 0; q < 4; q++) {
            int c = q * 256 + t;
            int row = c >> 3, cc = c & 7;
            int col8 = cc ^ (row & 7);
            GLOAD_LDS16(&W[(size_t)(n0 + row) * EMB + k0 + col8 * 8],
                        &sB[(q * 256 + wbase) * 8]);
        }
        __syncthreads();
        // two 32-k sub-chunks; fragments loaded per sub-chunk to bound VGPR
#pragma unroll
        for (int s = 0; s < 2; s++) {
            bf16x8 af[MI], bfr[4];
#pragma unroll
            for (int mi = 0; mi < MI; mi++) {
                int row = wm * (MI * 16) + mi * 16 + lr;
                af[mi] = ldfrag(&sA[(row * 8 + ((s * 4 + lq) ^ (row & 7))) * 8]);
            }
#pragma unroll
            for (int ni = 0; ni < 4; ni++) {
                int row = wn * 64 + ni * 16 + lr;
                bfr[ni] = ldfrag(&sB[(row * 8 + ((s * 4 + lq) ^ (row & 7))) * 8]);
            }
            // C^T: A-op = W-frag (rows = n), B-op = x-frag (rows = s)
#pragma unroll
            for (int mi = 0; mi < MI; mi++)
#pragma unroll
                for (int ni = 0; ni < 4; ni++)
                    acc[mi][ni] = MFMA16(bfr[ni], af[mi], acc[mi][ni]);
        }
    }

    // mode 1 reuses sA/sB for tanh(K); main-loop frag reads must be done
    if (mode == 1) __syncthreads();
    u16* sU = (w < 2) ? &sA[(size_t)w * 4096] : &sB[(size_t)(w - 2) * 4096];

    const float lamf = lam[0];
    const float qsc = 0.125f * LOG2E, lsc = lamf * LOG2E;
#pragma unroll
    for (int mi = 0; mi < MI; mi++)
#pragma unroll
        for (int ni = 0; ni < 4; ni++) {
            // C^T mapping: col (lr) = s axis, row (lq*4+r) = n/d axis
            const int sg = m0 + wm * (MI * 16) + mi * 16 + lr;
            const int ng = n0 + wn * 64 + ni * 16 + lq * 4;   // 4 consecutive n
            const float4 bv4 = *(const float4*)&bias[ng];
            const float v0 = acc[mi][ni][0] + bv4.x;
            const float v1 = acc[mi][ni][1] + bv4.y;
            const float v2 = acc[mi][ni][2] + bv4.z;
            const float v3 = acc[mi][ni][3] + bv4.w;
            if (mode == 3) {
                float4 o = {v0, v1, v2, v3};
                *(float4*)&out[(size_t)sg * EMB + ng] = o;
            } else {
                const int b = sg >> 11, s0 = sg & 2047;
                const int h = ng >> 6, d0 = ng & 63;
                if (mode == 0) {
                    size_t i128 = ((size_t)(b * NH + h) * SEQ + s0) * 128 + d0;
                    *(u16x4*)&Qa[i128] = pack4(v0 * qsc, v1 * qsc, v2 * qsc, v3 * qsc);
                    *(u16x4*)&Qa[i128 + 64] =
                        pack4(lsc * fast_tanh(v0), lsc * fast_tanh(v1),
                              lsc * fast_tanh(v2), lsc * fast_tanh(v3));
                } else if (mode == 1) {
                    *(u16x4*)&Ka[((size_t)(b * NH + h) * SEQ + s0) * 128 + d0] =
                        pack4(v0, v1, v2, v3);
                    // stage tanh(K) into per-wave LDS [64][64], XOR chunk swizzle
                    const int sl = mi * 16 + lr;             // local s row
                    const int chunk = (d0 >> 3) ^ (sl & 7);
                    *(u16x4*)&sU[sl * 64 + chunk * 8 + (d0 & 7)] =
                        pack4(fast_tanh(v0), fast_tanh(v1),
                              fast_tanh(v2), fast_tanh(v3));
                } else {
#pragma unroll
                    for (int r = 0; r < 4; r++) {
                        float vr = (r == 0) ? v0 : (r == 1) ? v1 : (r == 2) ? v2 : v3;
                        Vt[((size_t)(b * NH + h) * HD + d0 + r) * SEQ + s0] = f2b(vr);
                    }
                }
            }
        }

    // fused U kernel: Ka[:,64:128] = tanh(K) @ J_h^T (C^T orientation:
    // A-op = J rows (d_out), B-op = tanh rows (s))
    if (mode == 1) {
        const int hn = (n0 >> 6) + wn;
        const u16* Jh = Jb + (size_t)hn * 4096;
        bf16x8 jf[4][2];
#pragma unroll
        for (int nt = 0; nt < 4; nt++)
#pragma unroll
            for (int s2 = 0; s2 < 2; s2++)
                jf[nt][s2] = ldfrag(&Jh[(nt * 16 + lr) * 64 + s2 * 32 + lq * 8]);
#pragma unroll
        for (int rt2 = 0; rt2 < 4; rt2++) {
            int r64 = rt2 * 16 + lr;
            bf16x8 a0 = ldfrag(&sU[r64 * 64 + ((0 + lq) ^ (r64 & 7)) * 8]);
            bf16x8 a1 = ldfrag(&sU[r64 * 64 + ((4 + lq) ^ (r64 & 7)) * 8]);
            const int grow = m0 + wm * 64 + rt2 * 16 + lr;   // s (col axis)
            const int bb = grow >> 11, ss = grow & 2047;
            const size_t kbase = ((size_t)(bb * NH + hn) * SEQ + ss) * 128 + 64;
#pragma unroll
            for (int nt = 0; nt < 4; nt++) {
                f32x4 acc2 = {0.f, 0.f, 0.f, 0.f};
                acc2 = MFMA16(jf[nt][0], a0, acc2);
                acc2 = MFMA16(jf[nt][1], a1, acc2);
                *(u16x4*)&Ka[kbase + nt * 16 + lq * 4] =
                    pack4(acc2[0], acc2[1], acc2[2], acc2[3]);
            }
        }
    }
}

// ---------------------------------------------------------------------------
// Causal flash, S^T formulation, BM=128, 256 blocks x 512 thr (8 waves),
// segments (qt=p, qt=15-p) per block = uniform 17 k-tiles of KVBLK=128.
// (unchanged from round 4)
// ---------------------------------------------------------------------------
__global__ __launch_bounds__(512) void flash(
        const u16* __restrict__ Qa, const u16* __restrict__ Ka,
        const u16* __restrict__ Vt, u16* __restrict__ attn)
{
    __shared__ __attribute__((aligned(16))) u16 sK[2][128 * 128];  // 64 KB
    __shared__ __attribute__((aligned(16))) u16 sVt[2][64 * 128];  // 32 KB
    __shared__ __attribute__((aligned(16))) u16 sP[128 * 136];     // 34 KB
    __shared__ float sLs[2][4][64][2];                             // 4 KB

    const int t = threadIdx.x, w = t >> 6, L = t & 63, lr = L & 15, lq = L >> 4;
    const int wq = w & 3, wk = w >> 2;
    const int bh = blockIdx.x & 31, p = blockIdx.x >> 5;
    const int i_l = wq * 16 + lr;           // lane's q-row within a 64-set
    const u16* Kbase = Ka + (size_t)bh * SEQ * 128;
    const u16* Vbase = Vt + (size_t)bh * HD * SEQ;
    const int b = bh >> 4, h = bh & 15;
    float* sOt = reinterpret_cast<float*>(sK);   // 32 KB combine buffer (fits)

    // per-lane staging addresses (pre-swizzled source, linear LDS dest):
    // K tile 128x128: 2048 chunks (16/row), col8 = cc ^ (row&15), 4 per lane
    // V^T tile 64x128: 1024 chunks (16/row), j8 = cc ^ (d&7),     2 per lane
    const u16* kq[4];
#pragma unroll
    for (int q = 0; q < 4; q++) {
        int c = q * 512 + t;
        int row = c >> 4, cc = c & 15;
        kq[q] = Kbase + (size_t)row * 128 + (cc ^ (row & 15)) * 8;
    }
    const u16* vq[2];
#pragma unroll
    for (int q = 0; q < 2; q++) {
        int c = q * 512 + t;
        int d = c >> 4, cc = c & 15;
        vq[q] = Vbase + (size_t)d * SEQ + (cc ^ (d & 7)) * 8;
    }

#pragma unroll 1
    for (int seg = 0; seg < 2; seg++) {
        const int qt = seg ? 15 - p : p;
        const int qm = qt * 128;

        // two Q B-operand sets: set g covers q-rows qm + g*64 + [0,64)
        bf16x8 qf[2][4];
#pragma unroll
        for (int g = 0; g < 2; g++) {
            const u16* qrow = Qa + ((size_t)bh * SEQ + qm + g * 64 + i_l) * 128;
#pragma unroll
            for (int s = 0; s < 4; s++) qf[g][s] = ldfrag(qrow + s * 32 + lq * 8);
        }

        f32x4 Ot[2][4];
#pragma unroll
        for (int g = 0; g < 2; g++)
#pragma unroll
            for (int i = 0; i < 4; i++) { f32x4 z = {0.f, 0.f, 0.f, 0.f}; Ot[g][i] = z; }
        float lsum[2] = {0.f, 0.f};

        // prologue: stage tile 0 into buffer 0
        {
            int4 a0 = *(const int4*)kq[0];
            int4 a1 = *(const int4*)kq[1];
            int4 a2 = *(const int4*)kq[2];
            int4 a3 = *(const int4*)kq[3];
            int4 b0 = *(const int4*)vq[0];
            int4 b1 = *(const int4*)vq[1];
            *(int4*)&sK[0][(size_t)(0 * 512 + t) * 8] = a0;
            *(int4*)&sK[0][(size_t)(1 * 512 + t) * 8] = a1;
            *(int4*)&sK[0][(size_t)(2 * 512 + t) * 8] = a2;
            *(int4*)&sK[0][(size_t)(3 * 512 + t) * 8] = a3;
            *(int4*)&sVt[0][(size_t)(0 * 512 + t) * 8] = b0;
            *(int4*)&sVt[0][(size_t)(1 * 512 + t) * 8] = b1;
        }
        __syncthreads();

        int cur = 0;
        for (int kt = 0; kt <= qt; kt++) {
            // issue next tile's global loads FIRST: latency hides under compute
            const bool pf = kt < qt;
            int4 rk0, rk1, rk2, rk3, rv0, rv1;
            if (pf) {
                const int kn = (kt + 1) * 128;
                rk0 = *(const int4*)(kq[0] + (size_t)kn * 128);
                rk1 = *(const int4*)(kq[1] + (size_t)kn * 128);
                rk2 = *(const int4*)(kq[2] + (size_t)kn * 128);
                rk3 = *(const int4*)(kq[3] + (size_t)kn * 128);
                rv0 = *(const int4*)(vq[0] + kn);
                rv1 = *(const int4*)(vq[1] + kn);
            }
            const u16* sKc = sK[cur];
            const u16* sVc = sVt[cur];

            // S^T: group wk owns k-rows [wk*64, wk*64+64); each kf feeds 2 Q sets
            f32x4 sc[2][4];
#pragma unroll
            for (int g = 0; g < 2; g++)
#pragma unroll
                for (int m = 0; m < 4; m++) { f32x4 z = {0.f,0.f,0.f,0.f}; sc[g][m] = z; }
            __builtin_amdgcn_s_setprio(1);
#pragma unroll
            for (int mt2 = 0; mt2 < 4; mt2++) {
                int j = wk * 64 + mt2 * 16 + lr;
#pragma unroll
                for (int s = 0; s < 4; s++) {
                    bf16x8 kf = ldfrag(&sKc[(j * 16 + ((s * 4 + lq) ^ (j & 15))) * 8]);
                    sc[0][mt2] = MFMA16(kf, qf[0][s], sc[0][mt2]);
                    sc[1][mt2] = MFMA16(kf, qf[1][s], sc[1][mt2]);
                }
            }
            __builtin_amdgcn_s_setprio(0);
            // causal mask: only the diagonal tile (kt == qt)
            if (kt == qt) {
#pragma unroll
                for (int mt2 = 0; mt2 < 4; mt2++)
#pragma unroll
                    for (int r = 0; r < 4; r++) {
                        int jj = wk * 64 + mt2 * 16 + lq * 4 + r;
                        if (jj > i_l)      sc[0][mt2][r] = -INFINITY;
                        if (jj > 64 + i_l) sc[1][mt2][r] = -INFINITY;
                    }
            }
            // no-max softmax: P = exp2(s); raw v_exp_f32 (exp2(-inf)=0 masked)
#pragma unroll
            for (int g = 0; g < 2; g++) {
#pragma unroll
                for (int mt2 = 0; mt2 < 4; mt2++) {
                    float e0 = __builtin_amdgcn_exp2f(sc[g][mt2][0]);
                    float e1 = __builtin_amdgcn_exp2f(sc[g][mt2][1]);
                    float e2 = __builtin_amdgcn_exp2f(sc[g][mt2][2]);
                    float e3 = __builtin_amdgcn_exp2f(sc[g][mt2][3]);
                    lsum[g] += (e0 + e1) + (e2 + e3);
                    *(u16x4*)&sP[(g * 64 + i_l) * 136 + wk * 64 + mt2 * 16 + lq * 4] =
                        pack4(e0, e1, e2, e3);
                }
            }
            // O^T += V^T @ P^T over this group's 64-k slice (2 k-frags)
            __builtin_amdgcn_s_setprio(1);
#pragma unroll
            for (int s2l = 0; s2l < 2; s2l++) {
                bf16x8 pf0 = ldfrag(&sP[(i_l) * 136 + wk * 64 + s2l * 32 + lq * 8]);
                bf16x8 pf1 = ldfrag(&sP[(64 + i_l) * 136 + wk * 64 + s2l * 32 + lq * 8]);
#pragma unroll
                for (int mt = 0; mt < 4; mt++) {
                    int d = mt * 16 + lr;
                    bf16x8 vf = ldfrag(
                        &sVc[(d * 16 + ((wk * 8 + s2l * 4 + lq) ^ (d & 7))) * 8]);
                    Ot[0][mt] = MFMA16(vf, pf0, Ot[0][mt]);
                    Ot[1][mt] = MFMA16(vf, pf1, Ot[1][mt]);
                }
            }
            __builtin_amdgcn_s_setprio(0);
            // write prefetched tile into buf^1 (vmcnt wait lands here, hidden)
            if (pf) {
                *(int4*)&sK[cur ^ 1][(size_t)(0 * 512 + t) * 8] = rk0;
                *(int4*)&sK[cur ^ 1][(size_t)(1 * 512 + t) * 8] = rk1;
                *(int4*)&sK[cur ^ 1][(size_t)(2 * 512 + t) * 8] = rk2;
                *(int4*)&sK[cur ^ 1][(size_t)(3 * 512 + t) * 8] = rk3;
                *(int4*)&sVt[cur ^ 1][(size_t)(0 * 512 + t) * 8] = rv0;
                *(int4*)&sVt[cur ^ 1][(size_t)(1 * 512 + t) * 8] = rv1;
            }
            __syncthreads();
            cur ^= 1;
        }

        // ---- combine k-split partials and write this segment's output ----
        // sOt lane-major: element e of lane (wq*64+L) at sOt[wq*64+L + 256*e]
#pragma unroll
        for (int g = 0; g < 2; g++) {
            lsum[g] += __shfl_xor(lsum[g], 16);
            lsum[g] += __shfl_xor(lsum[g], 32);
            sLs[wk][wq][L][g] = lsum[g];
        }
        if (wk == 1) {
            float* dst = &sOt[wq * 64 + L];
#pragma unroll
            for (int g = 0; g < 2; g++)
#pragma unroll
                for (int mt = 0; mt < 4; mt++)
#pragma unroll
                    for (int r = 0; r < 4; r++)
                        dst[256 * (g * 16 + mt * 4 + r)] = Ot[g][mt][r];
        }
        __syncthreads();
        if (wk == 0) {
            const float* src = &sOt[wq * 64 + L];
#pragma unroll
            for (int g = 0; g < 2; g++) {
                float ls = lsum[g] + sLs[1][wq][L][g];
                const float r0 = __builtin_amdgcn_rcpf(ls);
                const float inv = r0 * (2.0f - ls * r0);  // NR refine
                const size_t base =
                    ((size_t)(b * SEQ + qm + g * 64 + i_l)) * EMB + h * HD;
#pragma unroll
                for (int mt = 0; mt < 4; mt++)
                    *(u16x4*)&attn[base + mt * 16 + lq * 4] = pack4(
                        (Ot[g][mt][0] + src[256 * (g * 16 + mt * 4 + 0)]) * inv,
                        (Ot[g][mt][1] + src[256 * (g * 16 + mt * 4 + 1)]) * inv,
                        (Ot[g][mt][2] + src[256 * (g * 16 + mt * 4 + 2)]) * inv,
                        (Ot[g][mt][3] + src[256 * (g * 16 + mt * 4 + 3)]) * inv);
            }
        }
        __syncthreads();   // protect sOt/sLs before next segment's staging
    }
}

// ---------------------------------------------------------------------------
extern "C" void kernel_launch(void* const* d_in, const int* in_sizes, int n_in,
                              void* d_out, int out_size, void* d_ws, size_t ws_size,
                              hipStream_t stream)
{
    const float* x   = (const float*)d_in[0];
    const float* Wq  = (const float*)d_in[1];
    const float* bq  = (const float*)d_in[2];
    const float* Wk  = (const float*)d_in[3];
    const float* bk  = (const float*)d_in[4];
    const float* Wv  = (const float*)d_in[5];
    const float* bv  = (const float*)d_in[6];
    const float* Wo  = (const float*)d_in[7];
    const float* bo  = (const float*)d_in[8];
    const float* J   = (const float*)d_in[9];
    const float* lam = (const float*)d_in[10];

    u16* ws  = (u16*)d_ws;
    u16* xb  = ws;                                   // 4096*1024 bf16 (reused as attn)
    u16* Wqb = xb  + (size_t)4096 * 1024;
    u16* Wkb = Wqb + (size_t)1024 * 1024;
    u16* Wvb = Wkb + (size_t)1024 * 1024;
    u16* Wob = Wvb + (size_t)1024 * 1024;
    u16* Qa  = Wob + (size_t)1024 * 1024;            // 32*2048*128
    u16* Ka  = Qa  + (size_t)32 * 2048 * 128;        // 32*2048*128
    u16* Vt  = Ka  + (size_t)32 * 2048 * 128;        // 32*64*2048 (b,h,d,s)
    u16* Jb  = Vt  + (size_t)32 * 64 * 2048;         // 16*64*64 bf16 (= ws+29360128)
    u16* attn = xb;                                  // alias: xb dead after QKV
    float* dout = (float*)d_out;

    dim3 blk(256);
    // fp32 -> bf16 for x, the four weight matrices, and J
    cvt_all<<<dim3(4128), blk, 0, stream>>>(x, Wq, Wk, Wv, Wo, J, ws);
    // fused Q/K/V projections (BK=64); mode 1 also produces Ka[:,64:128]
    gemm_epi<4><<<dim3(8, 32, 3), blk, 0, stream>>>(
        xb, Wqb, bq, Wkb, bk, Wvb, bv, lam, Jb, Qa, Ka, Vt, dout, 0);
    // causal flash attention: 256 blocks x 512 thr, qt pair (p, 15-p) per block
    flash<<<dim3(256), dim3(512), 0, stream>>>(Qa, Ka, Vt, attn);
    // output projection (64-row tiles -> 512 blocks for occupancy)
    gemm_epi<2><<<dim3(8, 64, 1), blk, 0, stream>>>(
        attn, Wob, bo, Wob, bo, Wob, bo, lam, Jb, Qa, Ka, Vt, dout, 3);
}